// Round 1
// baseline (478.602 us; speedup 1.0000x reference)
//
#include <hip/hip_runtime.h>
#include <hip/hip_bf16.h>

// Problem constants (B=8,S=2048,H=16,D=80 -> DM=1280, M=B*S=16384)
#define M_TOT   16384
#define DMODEL  1280
#define NHEAD   16
#define DHEAD   80
#define NT_COLS 10      // 1280 / 128 column tiles per matrix

typedef __attribute__((ext_vector_type(8))) __bf16 bf16x8;
typedef __attribute__((ext_vector_type(4))) float  f32x4;

__device__ __forceinline__ void gload16(const void* g, void* l) {
  __builtin_amdgcn_global_load_lds(
      (const __attribute__((address_space(1))) void*)g,
      (__attribute__((address_space(3))) void*)l, 16, 0, 0);
}

// ---------------- fp32 -> bf16 convert, vectorized ----------------
__global__ __launch_bounds__(256) void cvt_bf16_kernel(
    const float* __restrict__ x, __hip_bfloat16* __restrict__ y, int n4) {
  int i = blockIdx.x * 256 + threadIdx.x;
  if (i >= n4) return;
  float4 v = ((const float4*)x)[i];
  union { ushort4 u; __hip_bfloat16 h[4]; } o;
  o.h[0] = __float2bfloat16(v.x);
  o.h[1] = __float2bfloat16(v.y);
  o.h[2] = __float2bfloat16(v.z);
  o.h[3] = __float2bfloat16(v.w);
  ((ushort4*)y)[i] = o.u;
}

// ---------------- W [K][N] fp32  ->  Wt [N][K] bf16 ----------------
__global__ __launch_bounds__(256) void transpose_cvt_kernel(
    const float* __restrict__ W0, const float* __restrict__ W1,
    const float* __restrict__ W2, const float* __restrict__ W3,
    __hip_bfloat16* __restrict__ T0, __hip_bfloat16* __restrict__ T1,
    __hip_bfloat16* __restrict__ T2, __hip_bfloat16* __restrict__ T3) {
  const float* W = blockIdx.z == 0 ? W0 : blockIdx.z == 1 ? W1
                 : blockIdx.z == 2 ? W2 : W3;
  __hip_bfloat16* T = blockIdx.z == 0 ? T0 : blockIdx.z == 1 ? T1
                    : blockIdx.z == 2 ? T2 : T3;
  __shared__ float tile[32][33];
  int bx = blockIdx.x * 32, by = blockIdx.y * 32;
  int tx = threadIdx.x, ty = threadIdx.y;   // block (32,8)
  for (int j = 0; j < 32; j += 8)
    tile[ty + j][tx] = W[(size_t)(by + ty + j) * DMODEL + bx + tx];
  __syncthreads();
  for (int j = 0; j < 32; j += 8)
    T[(size_t)(bx + ty + j) * DMODEL + by + tx] = __float2bfloat16(tile[tx][ty + j]);
}

// ---------------- GEMM: C[M][N] = A[M][K] @ Bt[N][K]^T + bias ----------------
// m97 structure: 128x128 tile, BK=64, 4 waves (each 64x64), global_load_lds
// width-16 staging, mfma_f32_16x16x32_bf16. A and B fragments use the SAME
// (lane>>4)*8+j k-slot mapping so any HW K-permutation cancels.
template <bool OUT_BF16>
__global__ __launch_bounds__(256) void gemm_bt_kernel(
    const __hip_bfloat16* __restrict__ A,   // [M][K]
    const __hip_bfloat16* __restrict__ Bt0, // [N][K] (= W^T)
    const __hip_bfloat16* __restrict__ Bt1,
    const __hip_bfloat16* __restrict__ Bt2,
    const float* __restrict__ bias0, const float* __restrict__ bias1,
    const float* __restrict__ bias2,
    void* __restrict__ C0, void* __restrict__ C1, void* __restrict__ C2,
    int K, int N) {
  const int mat   = blockIdx.y / NT_COLS;
  const int ntile = blockIdx.y % NT_COLS;
  const __hip_bfloat16* Bt = mat == 0 ? Bt0 : mat == 1 ? Bt1 : Bt2;
  const float* bias        = mat == 0 ? bias0 : mat == 1 ? bias1 : bias2;
  void* C                  = mat == 0 ? C0 : mat == 1 ? C1 : C2;

  const int bm = blockIdx.x * 128;
  const int bn = ntile * 128;

  __shared__ __align__(16) __hip_bfloat16 As[128 * 64];
  __shared__ __align__(16) __hip_bfloat16 Bs[128 * 64];

  const int tid  = threadIdx.x;
  const int lane = tid & 63;
  const int w    = tid >> 6;           // wave id 0..3
  const int wm   = (w >> 1) * 64;      // wave row offset in tile
  const int wn   = (w & 1) * 64;       // wave col offset in tile

  f32x4 acc[4][4];
#pragma unroll
  for (int i = 0; i < 4; ++i)
#pragma unroll
    for (int j = 0; j < 4; ++j) acc[i][j] = (f32x4){0.f, 0.f, 0.f, 0.f};

  const int lrow = lane & 15;
  const int kofs = (lane >> 4) * 8;

  for (int kt = 0; kt < K; kt += 64) {
    // ---- stage A and B tiles (16 KB each) via global_load_lds ----
#pragma unroll
    for (int i = 0; i < 4; ++i) {
      int o   = w * 4096 + i * 1024 + lane * 16;  // byte offset in 16KB tile
      int row = o >> 7;                            // tile row (128B per row)
      int cb  = o & 127;                           // byte col within row
      gload16((const char*)A  + ((size_t)(bm + row) * K + kt) * 2 + cb,
              (char*)As + (w * 4096 + i * 1024));
      gload16((const char*)Bt + ((size_t)(bn + row) * K + kt) * 2 + cb,
              (char*)Bs + (w * 4096 + i * 1024));
    }
    __syncthreads();   // compiler emits vmcnt(0) drain before barrier

#pragma unroll
    for (int kk = 0; kk < 64; kk += 32) {
      bf16x8 af[4], bfr[4];
      const int lk = kk + kofs;
#pragma unroll
      for (int mi = 0; mi < 4; ++mi)
        af[mi] = *(const bf16x8*)(const void*)&As[(wm + mi * 16 + lrow) * 64 + lk];
#pragma unroll
      for (int ni = 0; ni < 4; ++ni)
        bfr[ni] = *(const bf16x8*)(const void*)&Bs[(wn + ni * 16 + lrow) * 64 + lk];
#pragma unroll
      for (int mi = 0; mi < 4; ++mi)
#pragma unroll
        for (int ni = 0; ni < 4; ++ni)
          acc[mi][ni] = __builtin_amdgcn_mfma_f32_16x16x32_bf16(
              af[mi], bfr[ni], acc[mi][ni], 0, 0, 0);
    }
    __syncthreads();
  }

  // ---- epilogue: C/D layout col=lane&15, row=(lane>>4)*4+r (m89-verified) ----
  const int rbase = (lane >> 4) * 4;
#pragma unroll
  for (int mi = 0; mi < 4; ++mi) {
#pragma unroll
    for (int ni = 0; ni < 4; ++ni) {
      const int col = bn + wn + ni * 16 + lrow;
      const float b = bias[col];
#pragma unroll
      for (int r = 0; r < 4; ++r) {
        const int row = bm + wm + mi * 16 + rbase + r;
        const float val = acc[mi][ni][r] + b;
        if (OUT_BF16)
          ((__hip_bfloat16*)C)[(size_t)row * N + col] = __float2bfloat16(val);
        else
          ((float*)C)[(size_t)row * N + col] = val;
      }
    }
  }
}

// ---------------- per-position head-mixing attention ----------------
// scores[h][t] = (q[h,:] . k[t,:]) / sqrt(80)  over heads (16x16), softmax
// over t, out[h][d] = sum_t p[h][t] v[t][d], * per_dim_scale[d].
__global__ __launch_bounds__(256) void attn_kernel(
    const __hip_bfloat16* __restrict__ q, const __hip_bfloat16* __restrict__ k,
    const __hip_bfloat16* __restrict__ v, const float* __restrict__ pds,
    __hip_bfloat16* __restrict__ out) {
  const size_t base = (size_t)blockIdx.x * DMODEL;
  __shared__ float qs[16][81], ks[16][81], vs[16][81];
  __shared__ float ps[16][17];
  const int tid = threadIdx.x;

  for (int i = tid; i < DMODEL; i += 256) {
    int h = i / DHEAD, d = i % DHEAD;
    qs[h][d] = __bfloat162float(q[base + i]);
    ks[h][d] = __bfloat162float(k[base + i]);
    vs[h][d] = __bfloat162float(v[base + i]);
  }
  __syncthreads();

  const int h = tid >> 4, t = tid & 15;
  float s = 0.f;
#pragma unroll
  for (int d = 0; d < DHEAD; ++d) s += qs[h][d] * ks[t][d];
  s *= 0.11180339887498948f;  // 1/sqrt(80)

  float m = s;
#pragma unroll
  for (int off = 8; off; off >>= 1) m = fmaxf(m, __shfl_xor(m, off, 16));
  float e = expf(s - m);
  float sum = e;
#pragma unroll
  for (int off = 8; off; off >>= 1) sum += __shfl_xor(sum, off, 16);
  ps[h][t] = e / sum;
  __syncthreads();

  for (int i = tid; i < DMODEL; i += 256) {
    int hh = i / DHEAD, d = i % DHEAD;
    float o = 0.f;
#pragma unroll
    for (int tt = 0; tt < 16; ++tt) o += ps[hh][tt] * vs[tt][d];
    o *= pds[d];
    out[base + i] = __float2bfloat16(o);
  }
}

// ---------------- launch ----------------
extern "C" void kernel_launch(void* const* d_in, const int* in_sizes, int n_in,
                              void* d_out, int out_size, void* d_ws, size_t ws_size,
                              hipStream_t stream) {
  const float* x   = (const float*)d_in[0];
  const float* Wq  = (const float*)d_in[1];
  const float* bq  = (const float*)d_in[2];
  const float* Wk  = (const float*)d_in[3];
  const float* bk  = (const float*)d_in[4];
  const float* Wv  = (const float*)d_in[5];
  const float* bv  = (const float*)d_in[6];
  const float* Wp  = (const float*)d_in[7];
  const float* bp  = (const float*)d_in[8];
  const float* pds = (const float*)d_in[9];
  float* out = (float*)d_out;

  char* ws = (char*)d_ws;
  const size_t ACT = (size_t)M_TOT * DMODEL * 2;      // 41,943,040 B
  const size_t WT  = (size_t)DMODEL * DMODEL * 2;     //  3,276,800 B
  __hip_bfloat16* xbf = (__hip_bfloat16*)(ws);
  __hip_bfloat16* qbf = (__hip_bfloat16*)(ws + ACT);
  __hip_bfloat16* kbf = (__hip_bfloat16*)(ws + 2 * ACT);
  __hip_bfloat16* vbf = (__hip_bfloat16*)(ws + 3 * ACT);
  __hip_bfloat16* wtq = (__hip_bfloat16*)(ws + 4 * ACT);
  __hip_bfloat16* wtk = (__hip_bfloat16*)(ws + 4 * ACT + WT);
  __hip_bfloat16* wtv = (__hip_bfloat16*)(ws + 4 * ACT + 2 * WT);
  __hip_bfloat16* wtp = (__hip_bfloat16*)(ws + 4 * ACT + 3 * WT);
  __hip_bfloat16* attnbf = xbf;  // alias: x is dead after the QKV GEMM

  // 1) x -> bf16
  {
    int n4 = (M_TOT * DMODEL) / 4;  // 5,242,880
    cvt_bf16_kernel<<<n4 / 256, 256, 0, stream>>>(x, xbf, n4);
  }
  // 2) transpose+convert the 4 weight matrices
  {
    dim3 g(DMODEL / 32, DMODEL / 32, 4), b(32, 8);
    transpose_cvt_kernel<<<g, b, 0, stream>>>(Wq, Wk, Wv, Wp, wtq, wtk, wtv, wtp);
  }
  // 3) fused QKV GEMM: grid.y = 3 * 10 column tiles
  {
    dim3 g(M_TOT / 128, 3 * NT_COLS);
    gemm_bt_kernel<true><<<g, 256, 0, stream>>>(
        xbf, wtq, wtk, wtv, bq, bk, bv, (void*)qbf, (void*)kbf, (void*)vbf,
        DMODEL, DMODEL);
  }
  // 4) per-position attention (+ per_dim_scale), bf16 out over xbf
  attn_kernel<<<M_TOT, 256, 0, stream>>>(qbf, kbf, vbf, pds, attnbf);
  // 5) output projection -> fp32 d_out
  {
    dim3 g(M_TOT / 128, NT_COLS);
    gemm_bt_kernel<false><<<g, 256, 0, stream>>>(
        attnbf, wtp, wtp, wtp, bp, bp, bp, (void*)out, (void*)out, (void*)out,
        DMODEL, DMODEL);
  }
}

// Round 2
// 450.029 us; speedup vs baseline: 1.0635x; 1.0635x over previous
//
#include <hip/hip_runtime.h>
#include <hip/hip_bf16.h>

// Problem constants (B=8,S=2048,H=16,D=80 -> DM=1280, M=B*S=16384)
#define M_TOT   16384
#define DMODEL  1280
#define NHEAD   16
#define DHEAD   80
#define NT_COLS 10      // 1280 / 128 column tiles per matrix
#define BK      64
#define NKT     (DMODEL / BK)   // 20 K-tiles

typedef __attribute__((ext_vector_type(8))) __bf16 bf16x8;
typedef __attribute__((ext_vector_type(4))) float  f32x4;

__device__ __forceinline__ void gload16(const void* g, void* l) {
  __builtin_amdgcn_global_load_lds(
      (const __attribute__((address_space(1))) void*)g,
      (__attribute__((address_space(3))) void*)l, 16, 0, 0);
}

// ---------------- fp32 -> bf16 convert, vectorized ----------------
__global__ __launch_bounds__(256) void cvt_bf16_kernel(
    const float* __restrict__ x, __hip_bfloat16* __restrict__ y, int n4) {
  int i = blockIdx.x * 256 + threadIdx.x;
  if (i >= n4) return;
  float4 v = ((const float4*)x)[i];
  union { ushort4 u; __hip_bfloat16 h[4]; } o;
  o.h[0] = __float2bfloat16(v.x);
  o.h[1] = __float2bfloat16(v.y);
  o.h[2] = __float2bfloat16(v.z);
  o.h[3] = __float2bfloat16(v.w);
  ((ushort4*)y)[i] = o.u;
}

// ---------------- W [K][N] fp32  ->  Wt [N][K] bf16 ----------------
__global__ __launch_bounds__(256) void transpose_cvt_kernel(
    const float* __restrict__ W0, const float* __restrict__ W1,
    const float* __restrict__ W2, const float* __restrict__ W3,
    __hip_bfloat16* __restrict__ T0, __hip_bfloat16* __restrict__ T1,
    __hip_bfloat16* __restrict__ T2, __hip_bfloat16* __restrict__ T3) {
  const float* W = blockIdx.z == 0 ? W0 : blockIdx.z == 1 ? W1
                 : blockIdx.z == 2 ? W2 : W3;
  __hip_bfloat16* T = blockIdx.z == 0 ? T0 : blockIdx.z == 1 ? T1
                    : blockIdx.z == 2 ? T2 : T3;
  __shared__ float tile[32][33];
  int bx = blockIdx.x * 32, by = blockIdx.y * 32;
  int tx = threadIdx.x, ty = threadIdx.y;   // block (32,8)
  for (int j = 0; j < 32; j += 8)
    tile[ty + j][tx] = W[(size_t)(by + ty + j) * DMODEL + bx + tx];
  __syncthreads();
  for (int j = 0; j < 32; j += 8)
    T[(size_t)(bx + ty + j) * DMODEL + by + tx] = __float2bfloat16(tile[tx][ty + j]);
}

// ---------------- GEMM: C[M][N] = A[M][K] @ Bt[N][K]^T + bias ----------------
// Ring-3 pipelined 256x128 tile, BK=64, 8 waves (each 64x64 output).
// T3/T4: global_load_lds prefetch distance 2, counted s_waitcnt vmcnt(6)
// (never drained to 0 in steady state), ONE raw s_barrier per K-tile.
// T2 (rule #21): LDS kept linear for global_load_lds; 16B-chunk XOR swizzle
// (c ^= row&7 within the 128B row) applied to the GLOBAL source address and
// to the ds_read_b128 address -> balanced 8 dword-accesses/bank.
// Race-freedom: stage at iter t writes ring slot (t+2)%3, whose readers
// (iter t-1) drained via lgkmcnt(0) before the t-1 barrier. vmcnt(6) at end
// of t retires exactly tile t+1's 6 loads (issue-order retirement).
template <bool OUT_BF16>
__global__ __launch_bounds__(512, 2) void gemm_bt_kernel(
    const __hip_bfloat16* __restrict__ A,   // [M][K]
    const __hip_bfloat16* __restrict__ Bt0, // [N][K] (= W^T)
    const __hip_bfloat16* __restrict__ Bt1,
    const __hip_bfloat16* __restrict__ Bt2,
    const float* __restrict__ bias0, const float* __restrict__ bias1,
    const float* __restrict__ bias2,
    void* __restrict__ C0, void* __restrict__ C1, void* __restrict__ C2,
    int N) {
  const int mat   = blockIdx.y / NT_COLS;
  const int ntile = blockIdx.y % NT_COLS;
  const __hip_bfloat16* Bt = mat == 0 ? Bt0 : mat == 1 ? Bt1 : Bt2;
  const float* bias        = mat == 0 ? bias0 : mat == 1 ? bias1 : bias2;
  void* C                  = mat == 0 ? C0 : mat == 1 ? C1 : C2;

  const int bm = blockIdx.x * 256;
  const int bn = ntile * 128;

  // ring-3 LDS: A 3x(256x64) bf16 = 96KB, B 3x(128x64) bf16 = 48KB
  __shared__ __align__(16) __hip_bfloat16 AsArr[3 * 256 * 64];
  __shared__ __align__(16) __hip_bfloat16 BsArr[3 * 128 * 64];

  const int tid  = threadIdx.x;
  const int lane = tid & 63;
  const int wid  = tid >> 6;            // 0..7
  const int wm   = (wid >> 1) * 64;     // wave row offset: 0,64,128,192
  const int wn   = (wid & 1) * 64;      // wave col offset: 0,64
  const int lrow = lane & 15;
  const int kofs = (lane >> 4) * 8;

  f32x4 acc[4][4];
#pragma unroll
  for (int i = 0; i < 4; ++i)
#pragma unroll
    for (int j = 0; j < 4; ++j) acc[i][j] = (f32x4){0.f, 0.f, 0.f, 0.f};

  // stage K-tile kt into ring slot `slot` (6 gloads/thread: 4 A + 2 B)
  auto stage = [&](int kt, int slot) {
    char* Ad = (char*)AsArr + slot * 32768 + wid * 1024;
    char* Bd = (char*)BsArr + slot * 16384 + wid * 1024;
#pragma unroll
    for (int i = 0; i < 4; ++i) {
      int o   = i * 8192 + tid * 16;
      int row = o >> 7;                 // 0..255
      int c   = (o >> 4) & 7;           // 16B chunk in 128B row
      gload16((const char*)A +
                  ((size_t)(bm + row) * DMODEL + kt * BK + ((c ^ (row & 7)) << 3)) * 2,
              Ad + i * 8192);
    }
#pragma unroll
    for (int i = 0; i < 2; ++i) {
      int o   = i * 8192 + tid * 16;
      int row = o >> 7;                 // 0..127
      int c   = (o >> 4) & 7;
      gload16((const char*)Bt +
                  ((size_t)(bn + row) * DMODEL + kt * BK + ((c ^ (row & 7)) << 3)) * 2,
              Bd + i * 8192);
    }
  };

  // prologue: tiles 0,1 -> slots 0,1; wait tile 0 landed (oldest 6 of 12)
  stage(0, 0);
  stage(1, 1);
  asm volatile("s_waitcnt vmcnt(6)" ::: "memory");
  __builtin_amdgcn_s_barrier();
  __builtin_amdgcn_sched_barrier(0);

  int cur = 0;
  for (int t = 0; t < NKT; ++t) {
    const bool pf = (t + 2 < NKT);
    if (pf) stage(t + 2, cur == 0 ? 2 : cur - 1);  // slot freed at iter t-1

    const int abase = cur * 16384;   // elements
    const int bbase = cur * 8192;
#pragma unroll
    for (int kk = 0; kk < BK; kk += 32) {
      const int g = (kk + kofs) >> 3;  // k chunk 0..7
      bf16x8 af[4], bv[4];
#pragma unroll
      for (int mi = 0; mi < 4; ++mi) {
        int r = wm + mi * 16 + lrow;
        af[mi] = *(const bf16x8*)(const void*)&AsArr[abase + r * 64 + ((g ^ (r & 7)) << 3)];
      }
#pragma unroll
      for (int ni = 0; ni < 4; ++ni) {
        int r = wn + ni * 16 + lrow;
        bv[ni] = *(const bf16x8*)(const void*)&BsArr[bbase + r * 64 + ((g ^ (r & 7)) << 3)];
      }
#pragma unroll
      for (int mi = 0; mi < 4; ++mi)
#pragma unroll
        for (int ni = 0; ni < 4; ++ni)
          acc[mi][ni] = __builtin_amdgcn_mfma_f32_16x16x32_bf16(
              af[mi], bv[ni], acc[mi][ni], 0, 0, 0);
    }
    __builtin_amdgcn_sched_barrier(0);
    if (pf) asm volatile("s_waitcnt vmcnt(6) lgkmcnt(0)" ::: "memory");
    else    asm volatile("s_waitcnt vmcnt(0) lgkmcnt(0)" ::: "memory");
    __builtin_amdgcn_s_barrier();
    __builtin_amdgcn_sched_barrier(0);
    cur = cur < 2 ? cur + 1 : 0;
  }

  // ---- epilogue: C/D layout col=lane&15, row=(lane>>4)*4+r (HW-verified R0) ----
  const int rbase = (lane >> 4) * 4;
#pragma unroll
  for (int mi = 0; mi < 4; ++mi) {
#pragma unroll
    for (int ni = 0; ni < 4; ++ni) {
      const int col = bn + wn + ni * 16 + lrow;
      const float b = bias[col];
#pragma unroll
      for (int r = 0; r < 4; ++r) {
        const int row = bm + wm + mi * 16 + rbase + r;
        const float val = acc[mi][ni][r] + b;
        if (OUT_BF16)
          ((__hip_bfloat16*)C)[(size_t)row * N + col] = __float2bfloat16(val);
        else
          ((float*)C)[(size_t)row * N + col] = val;
      }
    }
  }
}

// ---------------- per-position head-mixing attention ----------------
__global__ __launch_bounds__(256) void attn_kernel(
    const __hip_bfloat16* __restrict__ q, const __hip_bfloat16* __restrict__ k,
    const __hip_bfloat16* __restrict__ v, const float* __restrict__ pds,
    __hip_bfloat16* __restrict__ out) {
  const size_t base = (size_t)blockIdx.x * DMODEL;
  __shared__ float qs[16][81], ks[16][81], vs[16][81];
  __shared__ float ps[16][17];
  const int tid = threadIdx.x;

  for (int i = tid; i < DMODEL; i += 256) {
    int h = i / DHEAD, d = i % DHEAD;
    qs[h][d] = __bfloat162float(q[base + i]);
    ks[h][d] = __bfloat162float(k[base + i]);
    vs[h][d] = __bfloat162float(v[base + i]);
  }
  __syncthreads();

  const int h = tid >> 4, t = tid & 15;
  float s = 0.f;
#pragma unroll
  for (int d = 0; d < DHEAD; ++d) s += qs[h][d] * ks[t][d];
  s *= 0.11180339887498948f;  // 1/sqrt(80)

  float m = s;
#pragma unroll
  for (int off = 8; off; off >>= 1) m = fmaxf(m, __shfl_xor(m, off, 16));
  float e = expf(s - m);
  float sum = e;
#pragma unroll
  for (int off = 8; off; off >>= 1) sum += __shfl_xor(sum, off, 16);
  ps[h][t] = e / sum;
  __syncthreads();

  for (int i = tid; i < DMODEL; i += 256) {
    int hh = i / DHEAD, d = i % DHEAD;
    float o = 0.f;
#pragma unroll
    for (int tt = 0; tt < 16; ++tt) o += ps[hh][tt] * vs[tt][d];
    o *= pds[d];
    out[base + i] = __float2bfloat16(o);
  }
}

// ---------------- launch ----------------
extern "C" void kernel_launch(void* const* d_in, const int* in_sizes, int n_in,
                              void* d_out, int out_size, void* d_ws, size_t ws_size,
                              hipStream_t stream) {
  const float* x   = (const float*)d_in[0];
  const float* Wq  = (const float*)d_in[1];
  const float* bq  = (const float*)d_in[2];
  const float* Wk  = (const float*)d_in[3];
  const float* bk  = (const float*)d_in[4];
  const float* Wv  = (const float*)d_in[5];
  const float* bv  = (const float*)d_in[6];
  const float* Wp  = (const float*)d_in[7];
  const float* bp  = (const float*)d_in[8];
  const float* pds = (const float*)d_in[9];
  float* out = (float*)d_out;

  char* ws = (char*)d_ws;
  const size_t ACT = (size_t)M_TOT * DMODEL * 2;      // 41,943,040 B
  const size_t WT  = (size_t)DMODEL * DMODEL * 2;     //  3,276,800 B
  __hip_bfloat16* xbf = (__hip_bfloat16*)(ws);
  __hip_bfloat16* qbf = (__hip_bfloat16*)(ws + ACT);
  __hip_bfloat16* kbf = (__hip_bfloat16*)(ws + 2 * ACT);
  __hip_bfloat16* vbf = (__hip_bfloat16*)(ws + 3 * ACT);
  __hip_bfloat16* wtq = (__hip_bfloat16*)(ws + 4 * ACT);
  __hip_bfloat16* wtk = (__hip_bfloat16*)(ws + 4 * ACT + WT);
  __hip_bfloat16* wtv = (__hip_bfloat16*)(ws + 4 * ACT + 2 * WT);
  __hip_bfloat16* wtp = (__hip_bfloat16*)(ws + 4 * ACT + 3 * WT);
  __hip_bfloat16* attnbf = xbf;  // alias: x is dead after the QKV GEMM

  // 1) x -> bf16
  {
    int n4 = (M_TOT * DMODEL) / 4;  // 5,242,880
    cvt_bf16_kernel<<<n4 / 256, 256, 0, stream>>>(x, xbf, n4);
  }
  // 2) transpose+convert the 4 weight matrices
  {
    dim3 g(DMODEL / 32, DMODEL / 32, 4), b(32, 8);
    transpose_cvt_kernel<<<g, b, 0, stream>>>(Wq, Wk, Wv, Wp, wtq, wtk, wtv, wtp);
  }
  // 3) fused QKV GEMM: grid (M/256, 3*10)
  {
    dim3 g(M_TOT / 256, 3 * NT_COLS);
    gemm_bt_kernel<true><<<g, 512, 0, stream>>>(
        xbf, wtq, wtk, wtv, bq, bk, bv, (void*)qbf, (void*)kbf, (void*)vbf,
        DMODEL);
  }
  // 4) per-position attention (+ per_dim_scale), bf16 out over xbf
  attn_kernel<<<M_TOT, 256, 0, stream>>>(qbf, kbf, vbf, pds, attnbf);
  // 5) output projection -> fp32 d_out
  {
    dim3 g(M_TOT / 256, NT_COLS);
    gemm_bt_kernel<false><<<g, 512, 0, stream>>>(
        attnbf, wtp, wtp, wtp, bp, bp, bp, (void*)out, (void*)out, (void*)out,
        DMODEL);
  }
}

// Round 3
// 408.856 us; speedup vs baseline: 1.1706x; 1.1007x over previous
//
#include <hip/hip_runtime.h>
#include <hip/hip_bf16.h>

// Problem constants (B=8,S=2048,H=16,D=80 -> DM=1280, M=B*S=16384)
#define M_TOT   16384
#define DMODEL  1280
#define NHEAD   16
#define DHEAD   80
#define NTC     5          // 1280 / 256 column tiles per matrix
#define BK      64
#define NKT     (DMODEL / BK)   // 20 K-tiles

typedef __attribute__((ext_vector_type(8))) __bf16 bf16x8;
typedef __attribute__((ext_vector_type(4))) float  f32x4;

__device__ __forceinline__ void gload16(const void* g, void* l) {
  __builtin_amdgcn_global_load_lds(
      (const __attribute__((address_space(1))) void*)g,
      (__attribute__((address_space(3))) void*)l, 16, 0, 0);
}

__device__ __forceinline__ float bf2f(unsigned short u) {
  return __uint_as_float((unsigned)u << 16);
}

// ---------------- fp32 -> bf16 convert, vectorized ----------------
__global__ __launch_bounds__(256) void cvt_bf16_kernel(
    const float* __restrict__ x, __hip_bfloat16* __restrict__ y, int n4) {
  int i = blockIdx.x * 256 + threadIdx.x;
  if (i >= n4) return;
  float4 v = ((const float4*)x)[i];
  union { ushort4 u; __hip_bfloat16 h[4]; } o;
  o.h[0] = __float2bfloat16(v.x);
  o.h[1] = __float2bfloat16(v.y);
  o.h[2] = __float2bfloat16(v.z);
  o.h[3] = __float2bfloat16(v.w);
  ((ushort4*)y)[i] = o.u;
}

// ---------------- W [K][N] fp32  ->  Wt [N][K] bf16 ----------------
__global__ __launch_bounds__(256) void transpose_cvt_kernel(
    const float* __restrict__ W0, const float* __restrict__ W1,
    const float* __restrict__ W2, const float* __restrict__ W3,
    __hip_bfloat16* __restrict__ T0, __hip_bfloat16* __restrict__ T1,
    __hip_bfloat16* __restrict__ T2, __hip_bfloat16* __restrict__ T3) {
  const float* W = blockIdx.z == 0 ? W0 : blockIdx.z == 1 ? W1
                 : blockIdx.z == 2 ? W2 : W3;
  __hip_bfloat16* T = blockIdx.z == 0 ? T0 : blockIdx.z == 1 ? T1
                    : blockIdx.z == 2 ? T2 : T3;
  __shared__ float tile[32][33];
  int bx = blockIdx.x * 32, by = blockIdx.y * 32;
  int tx = threadIdx.x, ty = threadIdx.y;   // block (32,8)
  for (int j = 0; j < 32; j += 8)
    tile[ty + j][tx] = W[(size_t)(by + ty + j) * DMODEL + bx + tx];
  __syncthreads();
  for (int j = 0; j < 32; j += 8)
    T[(size_t)(bx + ty + j) * DMODEL + by + tx] = __float2bfloat16(tile[tx][ty + j]);
}

// ---------------- GEMM: C[M][N] = A[M][K] @ Bt[N][K]^T + bias ----------------
// 256x256 tile, BK=64, 8 waves (2M x 4N), per-wave 128x64 output.
// 4-phase-per-K-tile interleave (T3), double-buffered LDS (128 KiB),
// counted vmcnt drain once per K-tile (T4; forced to 0 by dbuf — last loads
// are L2-hot B-panel), setprio around MFMA clusters (T5), both-sides 16B-chunk
// XOR swizzle c^=row&7 (T2/rule #21) -> conflict-free ds_read_b128.
// B-fragments (8 x bf16x8) are loaded once per K-tile and held in registers
// across all 4 phases: 24 ds_read_b128 per wave per K-tile (0.375/MFMA).
template <bool OUT_BF16>
__global__ __launch_bounds__(512, 2) void gemm_bt_kernel(
    const __hip_bfloat16* __restrict__ A,   // [M][K]
    const __hip_bfloat16* __restrict__ Bt0, // [N][K] (= W^T)
    const __hip_bfloat16* __restrict__ Bt1,
    const __hip_bfloat16* __restrict__ Bt2,
    const float* __restrict__ bias0, const float* __restrict__ bias1,
    const float* __restrict__ bias2,
    void* __restrict__ C0, void* __restrict__ C1, void* __restrict__ C2) {
  const int mat   = blockIdx.y / NTC;
  const int ntile = blockIdx.y % NTC;
  const __hip_bfloat16* Bt = mat == 0 ? Bt0 : mat == 1 ? Bt1 : Bt2;
  const float* bias        = mat == 0 ? bias0 : mat == 1 ? bias1 : bias2;
  void* C                  = mat == 0 ? C0 : mat == 1 ? C1 : C2;

  const int bm = blockIdx.x * 256;
  const int bn = ntile * 256;

  __shared__ __align__(16) __hip_bfloat16 AsArr[2 * 256 * 64];  // 64 KiB
  __shared__ __align__(16) __hip_bfloat16 BsArr[2 * 256 * 64];  // 64 KiB

  const int tid  = threadIdx.x;
  const int lane = tid & 63;
  const int wid  = tid >> 6;            // 0..7
  const int wm   = (wid >> 2) * 128;    // wave row offset: 0,128
  const int wn   = (wid & 3) * 64;      // wave col offset: 0,64,128,192
  const int lrow = lane & 15;
  const int l4   = lane >> 4;           // 0..3

  // per-thread swizzled stage source pointers (4 A rounds + 4 B rounds)
  const char* srcA[4];
  const char* srcB[4];
#pragma unroll
  for (int i = 0; i < 4; ++i) {
    int o = i * 8192 + tid * 16;
    int row = o >> 7, c = (o >> 4) & 7;
    srcA[i] = (const char*)A  + ((size_t)(bm + row) * DMODEL + ((c ^ (row & 7)) << 3)) * 2;
    srcB[i] = (const char*)Bt + ((size_t)(bn + row) * DMODEL + ((c ^ (row & 7)) << 3)) * 2;
  }

  f32x4 acc[8][4];
#pragma unroll
  for (int i = 0; i < 8; ++i)
#pragma unroll
    for (int j = 0; j < 4; ++j) acc[i][j] = (f32x4){0.f, 0.f, 0.f, 0.f};

  // prologue: stage K-tile 0 into buffer 0
#pragma unroll
  for (int i = 0; i < 4; ++i) {
    gload16(srcA[i], (char*)AsArr + i * 8192 + wid * 1024);
    gload16(srcB[i], (char*)BsArr + i * 8192 + wid * 1024);
  }
  asm volatile("s_waitcnt vmcnt(0)" ::: "memory");
  __builtin_amdgcn_s_barrier();
  __builtin_amdgcn_sched_barrier(0);

  for (int t = 0; t < NKT; ++t) {
    const int buf = t & 1;
    const __hip_bfloat16* Ar = AsArr + buf * 16384;
    const __hip_bfloat16* Br = BsArr + buf * 16384;
    const size_t koff = (size_t)(t + 1) * (BK * 2);  // byte step in K
    const int nb = (buf ^ 1) * 32768;                // next-buffer byte offset
    const bool pf = (t + 1 < NKT);

    bf16x8 breg[2][4];
#pragma unroll
    for (int p = 0; p < 4; ++p) {
      // ---- ds-reads for this phase ----
      if (p == 0) {
#pragma unroll
        for (int ks = 0; ks < 2; ++ks)
#pragma unroll
          for (int ni = 0; ni < 4; ++ni) {
            int r = wn + ni * 16 + lrow, g = ks * 4 + l4;
            breg[ks][ni] = *(const bf16x8*)(const void*)&Br[r * 64 + ((g ^ (r & 7)) << 3)];
          }
      }
      bf16x8 areg[2][2];
#pragma unroll
      for (int ks = 0; ks < 2; ++ks)
#pragma unroll
        for (int j = 0; j < 2; ++j) {
          int r = wm + (2 * p + j) * 16 + lrow, g = ks * 4 + l4;
          areg[ks][j] = *(const bf16x8*)(const void*)&Ar[r * 64 + ((g ^ (r & 7)) << 3)];
        }
      // ---- stage 2 chunks of next tile (A early: long cover; B late: L2-hot) ----
      if (pf) {
        if (p == 0) {
          gload16(srcA[0] + koff, (char*)AsArr + nb + 0 * 8192 + wid * 1024);
          gload16(srcA[1] + koff, (char*)AsArr + nb + 1 * 8192 + wid * 1024);
        } else if (p == 1) {
          gload16(srcA[2] + koff, (char*)AsArr + nb + 2 * 8192 + wid * 1024);
          gload16(srcA[3] + koff, (char*)AsArr + nb + 3 * 8192 + wid * 1024);
        } else if (p == 2) {
          gload16(srcB[0] + koff, (char*)BsArr + nb + 0 * 8192 + wid * 1024);
          gload16(srcB[1] + koff, (char*)BsArr + nb + 1 * 8192 + wid * 1024);
        } else {
          gload16(srcB[2] + koff, (char*)BsArr + nb + 2 * 8192 + wid * 1024);
          gload16(srcB[3] + koff, (char*)BsArr + nb + 3 * 8192 + wid * 1024);
        }
      }
      __builtin_amdgcn_s_barrier();
      asm volatile("s_waitcnt lgkmcnt(0)" ::: "memory");
      __builtin_amdgcn_sched_barrier(0);
      __builtin_amdgcn_s_setprio(1);
#pragma unroll
      for (int j = 0; j < 2; ++j)
#pragma unroll
        for (int ni = 0; ni < 4; ++ni)
#pragma unroll
          for (int ks = 0; ks < 2; ++ks)
            acc[2 * p + j][ni] = __builtin_amdgcn_mfma_f32_16x16x32_bf16(
                areg[ks][j], breg[ks][ni], acc[2 * p + j][ni], 0, 0, 0);
      __builtin_amdgcn_s_setprio(0);
      __builtin_amdgcn_sched_barrier(0);
      if (p == 3 && pf) asm volatile("s_waitcnt vmcnt(0)" ::: "memory");
      __builtin_amdgcn_s_barrier();
    }
  }

  // ---- epilogue: C/D layout col=lane&15, row=(lane>>4)*4+r (HW-verified R1) ----
  const int rbase = l4 * 4;
#pragma unroll
  for (int mi = 0; mi < 8; ++mi) {
#pragma unroll
    for (int ni = 0; ni < 4; ++ni) {
      const int col = bn + wn + ni * 16 + lrow;
      const float b = bias[col];
#pragma unroll
      for (int r = 0; r < 4; ++r) {
        const int row = bm + wm + mi * 16 + rbase + r;
        const float val = acc[mi][ni][r] + b;
        if (OUT_BF16)
          ((__hip_bfloat16*)C)[(size_t)row * DMODEL + col] = __float2bfloat16(val);
        else
          ((float*)C)[(size_t)row * DMODEL + col] = val;
      }
    }
  }
}

// ---------------- per-position head-mixing attention ----------------
// scores[h][t] = (q[h,:] . k[t,:]) / sqrt(80) over heads (16x16), softmax
// over t, out[h][d] = sum_t p[h][t] v[t][d], * per_dim_scale[d].
// All global loads/stores vectorized bf16x8 (80 = 10 x 8, head-aligned).
__global__ __launch_bounds__(256) void attn_kernel(
    const __hip_bfloat16* __restrict__ q, const __hip_bfloat16* __restrict__ k,
    const __hip_bfloat16* __restrict__ v, const float* __restrict__ pds,
    __hip_bfloat16* __restrict__ out) {
  const size_t base = (size_t)blockIdx.x * DMODEL;
  __shared__ float qs[16][81], ks[16][81], vs[16][81];
  __shared__ float ps[16][17];
  const int tid = threadIdx.x;

  // 480 chunk loads (3 matrices x 160 bf16x8 chunks)
  for (int c = tid; c < 480; c += 256) {
    int matid = c / 160, idx = c - matid * 160;
    int h = idx / 10, d0 = (idx - h * 10) * 8;
    const __hip_bfloat16* src = matid == 0 ? q : matid == 1 ? k : v;
    union { bf16x8 v8; unsigned short u[8]; } uu;
    uu.v8 = *(const bf16x8*)(const void*)(src + base + (size_t)idx * 8);
    float* dst = (matid == 0 ? &qs[0][0] : matid == 1 ? &ks[0][0] : &vs[0][0]) +
                 h * 81 + d0;
#pragma unroll
    for (int j = 0; j < 8; ++j) dst[j] = bf2f(uu.u[j]);
  }
  __syncthreads();

  const int h = tid >> 4, t = tid & 15;
  float s = 0.f;
#pragma unroll
  for (int d = 0; d < DHEAD; ++d) s += qs[h][d] * ks[t][d];
  s *= 0.11180339887498948f;  // 1/sqrt(80)

  float m = s;
#pragma unroll
  for (int off = 8; off; off >>= 1) m = fmaxf(m, __shfl_xor(m, off, 16));
  float e = expf(s - m);
  float sum = e;
#pragma unroll
  for (int off = 8; off; off >>= 1) sum += __shfl_xor(sum, off, 16);
  ps[h][t] = e / sum;
  __syncthreads();

  // 160 output chunks, bf16x8 stores
  if (tid < 160) {
    int hh = tid / 10, d0 = (tid - hh * 10) * 8;
    union { bf16x8 v8; unsigned short u[8]; } oo;
#pragma unroll
    for (int j = 0; j < 8; ++j) {
      float o = 0.f;
#pragma unroll
      for (int tt = 0; tt < 16; ++tt) o += ps[hh][tt] * vs[tt][d0 + j];
      o *= pds[d0 + j];
      __hip_bfloat16 hb = __float2bfloat16(o);
      oo.u[j] = *(unsigned short*)&hb;
    }
    *(bf16x8*)(void*)(out + base + (size_t)tid * 8) = oo.v8;
  }
}

// ---------------- launch ----------------
extern "C" void kernel_launch(void* const* d_in, const int* in_sizes, int n_in,
                              void* d_out, int out_size, void* d_ws, size_t ws_size,
                              hipStream_t stream) {
  const float* x   = (const float*)d_in[0];
  const float* Wq  = (const float*)d_in[1];
  const float* bq  = (const float*)d_in[2];
  const float* Wk  = (const float*)d_in[3];
  const float* bk  = (const float*)d_in[4];
  const float* Wv  = (const float*)d_in[5];
  const float* bv  = (const float*)d_in[6];
  const float* Wp  = (const float*)d_in[7];
  const float* bp  = (const float*)d_in[8];
  const float* pds = (const float*)d_in[9];
  float* out = (float*)d_out;

  char* ws = (char*)d_ws;
  const size_t ACT = (size_t)M_TOT * DMODEL * 2;      // 41,943,040 B
  const size_t WT  = (size_t)DMODEL * DMODEL * 2;     //  3,276,800 B
  __hip_bfloat16* xbf = (__hip_bfloat16*)(ws);
  __hip_bfloat16* qbf = (__hip_bfloat16*)(ws + ACT);
  __hip_bfloat16* kbf = (__hip_bfloat16*)(ws + 2 * ACT);
  __hip_bfloat16* vbf = (__hip_bfloat16*)(ws + 3 * ACT);
  __hip_bfloat16* wtq = (__hip_bfloat16*)(ws + 4 * ACT);
  __hip_bfloat16* wtk = (__hip_bfloat16*)(ws + 4 * ACT + WT);
  __hip_bfloat16* wtv = (__hip_bfloat16*)(ws + 4 * ACT + 2 * WT);
  __hip_bfloat16* wtp = (__hip_bfloat16*)(ws + 4 * ACT + 3 * WT);
  __hip_bfloat16* attnbf = xbf;  // alias: x is dead after the QKV GEMM

  // 1) x -> bf16
  {
    int n4 = (M_TOT * DMODEL) / 4;  // 5,242,880
    cvt_bf16_kernel<<<n4 / 256, 256, 0, stream>>>(x, xbf, n4);
  }
  // 2) transpose+convert the 4 weight matrices
  {
    dim3 g(DMODEL / 32, DMODEL / 32, 4), b(32, 8);
    transpose_cvt_kernel<<<g, b, 0, stream>>>(Wq, Wk, Wv, Wp, wtq, wtk, wtv, wtp);
  }
  // 3) fused QKV GEMM: grid (M/256, 3*5)
  {
    dim3 g(M_TOT / 256, 3 * NTC);
    gemm_bt_kernel<true><<<g, 512, 0, stream>>>(
        xbf, wtq, wtk, wtv, bq, bk, bv, (void*)qbf, (void*)kbf, (void*)vbf);
  }
  // 4) per-position attention (+ per_dim_scale), bf16 out over xbf
  attn_kernel<<<M_TOT, 256, 0, stream>>>(qbf, kbf, vbf, pds, attnbf);
  // 5) output projection -> fp32 d_out
  {
    dim3 g(M_TOT / 256, NTC);
    gemm_bt_kernel<false><<<g, 512, 0, stream>>>(
        attnbf, wtp, wtp, wtp, bp, bp, bp, (void*)out, (void*)out, (void*)out);
  }
}

// Round 4
// 388.167 us; speedup vs baseline: 1.2330x; 1.0533x over previous
//
#include <hip/hip_runtime.h>
#include <hip/hip_bf16.h>

// Problem constants (B=8,S=2048,H=16,D=80 -> DM=1280, M=B*S=16384)
#define M_TOT   16384
#define DMODEL  1280
#define NHEAD   16
#define DHEAD   80
#define NTC     5          // 1280 / 256 column tiles per matrix
#define BK      64
#define NKT     (DMODEL / BK)   // 20 K-tiles

typedef __attribute__((ext_vector_type(8))) __bf16 bf16x8;
typedef __attribute__((ext_vector_type(4))) float  f32x4;

__device__ __forceinline__ void gload16(const void* g, void* l) {
  __builtin_amdgcn_global_load_lds(
      (const __attribute__((address_space(1))) void*)g,
      (__attribute__((address_space(3))) void*)l, 16, 0, 0);
}

__device__ __forceinline__ float bf2f(unsigned short u) {
  return __uint_as_float((unsigned)u << 16);
}

// ---------------- fp32 -> bf16 convert, vectorized ----------------
__global__ __launch_bounds__(256) void cvt_bf16_kernel(
    const float* __restrict__ x, __hip_bfloat16* __restrict__ y, int n4) {
  int i = blockIdx.x * 256 + threadIdx.x;
  if (i >= n4) return;
  float4 v = ((const float4*)x)[i];
  union { ushort4 u; __hip_bfloat16 h[4]; } o;
  o.h[0] = __float2bfloat16(v.x);
  o.h[1] = __float2bfloat16(v.y);
  o.h[2] = __float2bfloat16(v.z);
  o.h[3] = __float2bfloat16(v.w);
  ((ushort4*)y)[i] = o.u;
}

// ---------------- W [K][N] fp32  ->  Wt [N][K] bf16 ----------------
__global__ __launch_bounds__(256) void transpose_cvt_kernel(
    const float* __restrict__ W0, const float* __restrict__ W1,
    const float* __restrict__ W2, const float* __restrict__ W3,
    __hip_bfloat16* __restrict__ T0, __hip_bfloat16* __restrict__ T1,
    __hip_bfloat16* __restrict__ T2, __hip_bfloat16* __restrict__ T3) {
  const float* W = blockIdx.z == 0 ? W0 : blockIdx.z == 1 ? W1
                 : blockIdx.z == 2 ? W2 : W3;
  __hip_bfloat16* T = blockIdx.z == 0 ? T0 : blockIdx.z == 1 ? T1
                    : blockIdx.z == 2 ? T2 : T3;
  __shared__ float tile[32][33];
  int bx = blockIdx.x * 32, by = blockIdx.y * 32;
  int tx = threadIdx.x, ty = threadIdx.y;   // block (32,8)
  for (int j = 0; j < 32; j += 8)
    tile[ty + j][tx] = W[(size_t)(by + ty + j) * DMODEL + bx + tx];
  __syncthreads();
  for (int j = 0; j < 32; j += 8)
    T[(size_t)(bx + ty + j) * DMODEL + by + tx] = __float2bfloat16(tile[tx][ty + j]);
}

// 16-MFMA cluster: acc[MB..MB+3][0..3] += AF[j] x BF[n]
#define MFMA16(AF, BF, MB)                                                   \
  do {                                                                       \
    _Pragma("unroll")                                                        \
    for (int j_ = 0; j_ < 4; ++j_) {                                         \
      _Pragma("unroll")                                                      \
      for (int n_ = 0; n_ < 4; ++n_)                                         \
        acc[(MB) + j_][n_] = __builtin_amdgcn_mfma_f32_16x16x32_bf16(        \
            AF[j_], BF[n_], acc[(MB) + j_][n_], 0, 0, 0);                    \
    }                                                                        \
  } while (0)

// ---------------- GEMM: C[M][N] = A[M][K] @ Bt[N][K]^T + bias ----------------
// 256x256 tile, BK=64, 8 waves (2M x 4N), per-wave 128x64 output.
// Read-ahead-1 pipeline: phase p issues the ds_read_b128 frags for phase p+1,
// so LDS reads execute concurrently with phase p's MFMA cluster (the compiler
// inserts counted lgkmcnt for the visible deps). Phases per K-tile:
//   ph0 = (ks0, m0-3)  [reads A ks0 m4-7]        [gloads A(t+1)]
//   ph1 = (ks0, m4-7)  [reads A ks1 m0-3, B ks1] [gloads B(t+1)]
//   ph2 = (ks1, m0-3)  [reads A ks1 m4-7]        [end: vmcnt(0) -> t+1 landed]
//   ph3 = (ks1, m4-7)  [reads next-buffer A ks0 m0-3, B ks0]
// One s_barrier per phase. Double-buffered LDS (128 KiB), both-sides 16B-chunk
// XOR swizzle (conflict-free, verified 0 in R2/R3). Buffer flip = ^32768 on
// the 4 LDS base offsets (all tile offsets < 32 KiB).
template <bool OUT_BF16>
__global__ __launch_bounds__(512, 2) void gemm_bt_kernel(
    const __hip_bfloat16* __restrict__ A,   // [M][K]
    const __hip_bfloat16* __restrict__ Bt0, // [N][K] (= W^T)
    const __hip_bfloat16* __restrict__ Bt1,
    const __hip_bfloat16* __restrict__ Bt2,
    const float* __restrict__ bias0, const float* __restrict__ bias1,
    const float* __restrict__ bias2,
    void* __restrict__ C0, void* __restrict__ C1, void* __restrict__ C2) {
  const int mat   = blockIdx.y / NTC;
  const int ntile = blockIdx.y % NTC;
  const __hip_bfloat16* Bt = mat == 0 ? Bt0 : mat == 1 ? Bt1 : Bt2;
  const float* bias        = mat == 0 ? bias0 : mat == 1 ? bias1 : bias2;
  void* C                  = mat == 0 ? C0 : mat == 1 ? C1 : C2;

  const int bm = blockIdx.x * 256;
  const int bn = ntile * 256;

  __shared__ __align__(16) __hip_bfloat16 AsArr[2 * 256 * 64];  // 64 KiB
  __shared__ __align__(16) __hip_bfloat16 BsArr[2 * 256 * 64];  // 64 KiB

  const int tid  = threadIdx.x;
  const int lane = tid & 63;
  const int wid  = tid >> 6;            // 0..7
  const int wm   = (wid >> 2) * 128;    // wave row offset: 0,128
  const int wn   = (wid & 3) * 64;      // wave col offset: 0,64,128,192
  const int lrow = lane & 15;
  const int l4   = lane >> 4;           // 0..3

  // per-thread swizzled stage source pointers (4 A chunks + 4 B chunks)
  const char* srcA[4];
  const char* srcB[4];
#pragma unroll
  for (int i = 0; i < 4; ++i) {
    int o = i * 8192 + tid * 16;
    int row = o >> 7, c = (o >> 4) & 7;
    srcA[i] = (const char*)A  + ((size_t)(bm + row) * DMODEL + ((c ^ (row & 7)) << 3)) * 2;
    srcB[i] = (const char*)Bt + ((size_t)(bn + row) * DMODEL + ((c ^ (row & 7)) << 3)) * 2;
  }

  f32x4 acc[8][4];
#pragma unroll
  for (int i = 0; i < 8; ++i)
#pragma unroll
    for (int j = 0; j < 4; ++j) acc[i][j] = (f32x4){0.f, 0.f, 0.f, 0.f};

  // LDS read base offsets (bytes). Row r = w*+sub*16+lrow: (r&7)==(lrow&7)
  // since w*/16-multiples are 0 mod 8 -> swizzle XOR is lane-only.
  const int gx0 = (l4 ^ (lrow & 7)) << 4;        // ks0 chunk byte offset
  const int gx1 = ((4 + l4) ^ (lrow & 7)) << 4;  // ks1 chunk byte offset
  int aK0 = (wm + lrow) * 128 + gx0;
  int aK1 = (wm + lrow) * 128 + gx1;
  int bK0 = (wn + lrow) * 128 + gx0;
  int bK1 = (wn + lrow) * 128 + gx1;
  const char* Ab = (const char*)AsArr;
  const char* Bb = (const char*)BsArr;

  // prologue: stage K-tile 0 into buffer 0; first frag reads (ph0 of t=0)
#pragma unroll
  for (int i = 0; i < 4; ++i) {
    gload16(srcA[i], (char*)AsArr + i * 8192 + wid * 1024);
    gload16(srcB[i], (char*)BsArr + i * 8192 + wid * 1024);
  }
  asm volatile("s_waitcnt vmcnt(0)" ::: "memory");
  __builtin_amdgcn_s_barrier();

  bf16x8 aFa[4], aFb[4], bF0[4], bF1[4];
#pragma unroll
  for (int j = 0; j < 4; ++j) aFa[j] = *(const bf16x8*)(Ab + aK0 + j * 2048);
#pragma unroll
  for (int n = 0; n < 4; ++n) bF0[n] = *(const bf16x8*)(Bb + bK0 + n * 2048);
  __builtin_amdgcn_sched_barrier(0);

  for (int t = 0; t < NKT; ++t) {
    const bool last = (t == NKT - 1);
    const size_t koff = (size_t)(t + 1) * (BK * 2);
    const int nb = ((t + 1) & 1) * 32768;

    // ---------- phase 0: MFMA(ks0, m0-3) ----------
    __builtin_amdgcn_s_barrier();
#pragma unroll
    for (int j = 0; j < 4; ++j)
      aFb[j] = *(const bf16x8*)(Ab + aK0 + (4 + j) * 2048);
    if (!last) {
#pragma unroll
      for (int i = 0; i < 4; ++i)
        gload16(srcA[i] + koff, (char*)AsArr + nb + i * 8192 + wid * 1024);
    }
    __builtin_amdgcn_sched_barrier(0);
    __builtin_amdgcn_s_setprio(1);
    MFMA16(aFa, bF0, 0);
    __builtin_amdgcn_s_setprio(0);
    __builtin_amdgcn_sched_barrier(0);

    // ---------- phase 1: MFMA(ks0, m4-7) ----------
    __builtin_amdgcn_s_barrier();
#pragma unroll
    for (int j = 0; j < 4; ++j)
      aFa[j] = *(const bf16x8*)(Ab + aK1 + j * 2048);
#pragma unroll
    for (int n = 0; n < 4; ++n)
      bF1[n] = *(const bf16x8*)(Bb + bK1 + n * 2048);
    if (!last) {
#pragma unroll
      for (int i = 0; i < 4; ++i)
        gload16(srcB[i] + koff, (char*)BsArr + nb + i * 8192 + wid * 1024);
    }
    __builtin_amdgcn_sched_barrier(0);
    __builtin_amdgcn_s_setprio(1);
    MFMA16(aFb, bF0, 4);
    __builtin_amdgcn_s_setprio(0);
    __builtin_amdgcn_sched_barrier(0);

    // ---------- phase 2: MFMA(ks1, m0-3) ----------
    __builtin_amdgcn_s_barrier();
#pragma unroll
    for (int j = 0; j < 4; ++j)
      aFb[j] = *(const bf16x8*)(Ab + aK1 + (4 + j) * 2048);
    __builtin_amdgcn_sched_barrier(0);
    __builtin_amdgcn_s_setprio(1);
    MFMA16(aFa, bF1, 0);
    __builtin_amdgcn_s_setprio(0);
    __builtin_amdgcn_sched_barrier(0);
    if (!last) asm volatile("s_waitcnt vmcnt(0)" ::: "memory");

    // ---------- phase 3: MFMA(ks1, m4-7) ----------
    __builtin_amdgcn_s_barrier();
    if (!last) {
      aK0 ^= 32768; aK1 ^= 32768; bK0 ^= 32768; bK1 ^= 32768;
#pragma unroll
      for (int j = 0; j < 4; ++j)
        aFa[j] = *(const bf16x8*)(Ab + aK0 + j * 2048);
#pragma unroll
      for (int n = 0; n < 4; ++n)
        bF0[n] = *(const bf16x8*)(Bb + bK0 + n * 2048);
    }
    __builtin_amdgcn_sched_barrier(0);
    __builtin_amdgcn_s_setprio(1);
    MFMA16(aFb, bF1, 4);
    __builtin_amdgcn_s_setprio(0);
    __builtin_amdgcn_sched_barrier(0);
  }

  // ---- epilogue: C/D layout col=lane&15, row=(lane>>4)*4+r (HW-verified R1) ----
  const int rbase = l4 * 4;
#pragma unroll
  for (int mi = 0; mi < 8; ++mi) {
#pragma unroll
    for (int ni = 0; ni < 4; ++ni) {
      const int col = bn + wn + ni * 16 + lrow;
      const float b = bias[col];
#pragma unroll
      for (int r = 0; r < 4; ++r) {
        const int row = bm + wm + mi * 16 + rbase + r;
        const float val = acc[mi][ni][r] + b;
        if (OUT_BF16)
          ((__hip_bfloat16*)C)[(size_t)row * DMODEL + col] = __float2bfloat16(val);
        else
          ((float*)C)[(size_t)row * DMODEL + col] = val;
      }
    }
  }
}

// ---------------- per-position head-mixing attention ----------------
// scores[h][t] = (q[h,:] . k[t,:]) / sqrt(80) over heads (16x16), softmax
// over t, out[h][d] = sum_t p[h][t] v[t][d], * per_dim_scale[d].
// All global loads/stores vectorized bf16x8 (80 = 10 x 8, head-aligned).
__global__ __launch_bounds__(256) void attn_kernel(
    const __hip_bfloat16* __restrict__ q, const __hip_bfloat16* __restrict__ k,
    const __hip_bfloat16* __restrict__ v, const float* __restrict__ pds,
    __hip_bfloat16* __restrict__ out) {
  const size_t base = (size_t)blockIdx.x * DMODEL;
  __shared__ float qs[16][81], ks[16][81], vs[16][81];
  __shared__ float ps[16][17];
  const int tid = threadIdx.x;

  // 480 chunk loads (3 matrices x 160 bf16x8 chunks)
  for (int c = tid; c < 480; c += 256) {
    int matid = c / 160, idx = c - matid * 160;
    int h = idx / 10, d0 = (idx - h * 10) * 8;
    const __hip_bfloat16* src = matid == 0 ? q : matid == 1 ? k : v;
    union { bf16x8 v8; unsigned short u[8]; } uu;
    uu.v8 = *(const bf16x8*)(const void*)(src + base + (size_t)idx * 8);
    float* dst = (matid == 0 ? &qs[0][0] : matid == 1 ? &ks[0][0] : &vs[0][0]) +
                 h * 81 + d0;
#pragma unroll
    for (int j = 0; j < 8; ++j) dst[j] = bf2f(uu.u[j]);
  }
  __syncthreads();

  const int h = tid >> 4, t = tid & 15;
  float s = 0.f;
#pragma unroll
  for (int d = 0; d < DHEAD; ++d) s += qs[h][d] * ks[t][d];
  s *= 0.11180339887498948f;  // 1/sqrt(80)

  float m = s;
#pragma unroll
  for (int off = 8; off; off >>= 1) m = fmaxf(m, __shfl_xor(m, off, 16));
  float e = expf(s - m);
  float sum = e;
#pragma unroll
  for (int off = 8; off; off >>= 1) sum += __shfl_xor(sum, off, 16);
  ps[h][t] = e / sum;
  __syncthreads();

  // 160 output chunks, bf16x8 stores
  if (tid < 160) {
    int hh = tid / 10, d0 = (tid - hh * 10) * 8;
    union { bf16x8 v8; unsigned short u[8]; } oo;
#pragma unroll
    for (int j = 0; j < 8; ++j) {
      float o = 0.f;
#pragma unroll
      for (int tt = 0; tt < 16; ++tt) o += ps[hh][tt] * vs[tt][d0 + j];
      o *= pds[d0 + j];
      __hip_bfloat16 hb = __float2bfloat16(o);
      oo.u[j] = *(unsigned short*)&hb;
    }
    *(bf16x8*)(void*)(out + base + (size_t)tid * 8) = oo.v8;
  }
}

// ---------------- launch ----------------
extern "C" void kernel_launch(void* const* d_in, const int* in_sizes, int n_in,
                              void* d_out, int out_size, void* d_ws, size_t ws_size,
                              hipStream_t stream) {
  const float* x   = (const float*)d_in[0];
  const float* Wq  = (const float*)d_in[1];
  const float* bq  = (const float*)d_in[2];
  const float* Wk  = (const float*)d_in[3];
  const float* bk  = (const float*)d_in[4];
  const float* Wv  = (const float*)d_in[5];
  const float* bv  = (const float*)d_in[6];
  const float* Wp  = (const float*)d_in[7];
  const float* bp  = (const float*)d_in[8];
  const float* pds = (const float*)d_in[9];
  float* out = (float*)d_out;

  char* ws = (char*)d_ws;
  const size_t ACT = (size_t)M_TOT * DMODEL * 2;      // 41,943,040 B
  const size_t WT  = (size_t)DMODEL * DMODEL * 2;     //  3,276,800 B
  __hip_bfloat16* xbf = (__hip_bfloat16*)(ws);
  __hip_bfloat16* qbf = (__hip_bfloat16*)(ws + ACT);
  __hip_bfloat16* kbf = (__hip_bfloat16*)(ws + 2 * ACT);
  __hip_bfloat16* vbf = (__hip_bfloat16*)(ws + 3 * ACT);
  __hip_bfloat16* wtq = (__hip_bfloat16*)(ws + 4 * ACT);
  __hip_bfloat16* wtk = (__hip_bfloat16*)(ws + 4 * ACT + WT);
  __hip_bfloat16* wtv = (__hip_bfloat16*)(ws + 4 * ACT + 2 * WT);
  __hip_bfloat16* wtp = (__hip_bfloat16*)(ws + 4 * ACT + 3 * WT);
  __hip_bfloat16* attnbf = xbf;  // alias: x is dead after the QKV GEMM

  // 1) x -> bf16
  {
    int n4 = (M_TOT * DMODEL) / 4;  // 5,242,880
    cvt_bf16_kernel<<<n4 / 256, 256, 0, stream>>>(x, xbf, n4);
  }
  // 2) transpose+convert the 4 weight matrices
  {
    dim3 g(DMODEL / 32, DMODEL / 32, 4), b(32, 8);
    transpose_cvt_kernel<<<g, b, 0, stream>>>(Wq, Wk, Wv, Wp, wtq, wtk, wtv, wtp);
  }
  // 3) fused QKV GEMM: grid (M/256, 3*5)
  {
    dim3 g(M_TOT / 256, 3 * NTC);
    gemm_bt_kernel<true><<<g, 512, 0, stream>>>(
        xbf, wtq, wtk, wtv, bq, bk, bv, (void*)qbf, (void*)kbf, (void*)vbf);
  }
  // 4) per-position attention (+ per_dim_scale), bf16 out over xbf
  attn_kernel<<<M_TOT, 256, 0, stream>>>(qbf, kbf, vbf, pds, attnbf);
  // 5) output projection -> fp32 d_out
  {
    dim3 g(M_TOT / 256, NTC);
    gemm_bt_kernel<false><<<g, 512, 0, stream>>>(
        attnbf, wtp, wtp, wtp, bp, bp, bp, (void*)out, (void*)out, (void*)out);
  }
}

// Round 5
// 356.301 us; speedup vs baseline: 1.3433x; 1.0894x over previous
//
#include <hip/hip_runtime.h>
#include <hip/hip_bf16.h>

// Problem constants (B=8,S=2048,H=16,D=80 -> DM=1280, M=B*S=16384)
#define M_TOT   16384
#define DMODEL  1280
#define NHEAD   16
#define DHEAD   80
#define NTC     5          // 1280 / 256 column tiles per matrix
#define BK      64
#define NKT     (DMODEL / BK)   // 20 K-tiles

typedef __attribute__((ext_vector_type(8))) __bf16 bf16x8;
typedef __attribute__((ext_vector_type(4))) float  f32x4;

__device__ __forceinline__ void gload16(const void* g, void* l) {
  __builtin_amdgcn_global_load_lds(
      (const __attribute__((address_space(1))) void*)g,
      (__attribute__((address_space(3))) void*)l, 16, 0, 0);
}

__device__ __forceinline__ float bf2f(unsigned short u) {
  return __uint_as_float((unsigned)u << 16);
}

// ---------------- fp32 -> bf16 convert, vectorized ----------------
__global__ __launch_bounds__(256) void cvt_bf16_kernel(
    const float* __restrict__ x, __hip_bfloat16* __restrict__ y, int n4) {
  int i = blockIdx.x * 256 + threadIdx.x;
  if (i >= n4) return;
  float4 v = ((const float4*)x)[i];
  union { ushort4 u; __hip_bfloat16 h[4]; } o;
  o.h[0] = __float2bfloat16(v.x);
  o.h[1] = __float2bfloat16(v.y);
  o.h[2] = __float2bfloat16(v.z);
  o.h[3] = __float2bfloat16(v.w);
  ((ushort4*)y)[i] = o.u;
}

// ---------------- W [K][N] fp32  ->  Wt [N][K] bf16 ----------------
__global__ __launch_bounds__(256) void transpose_cvt_kernel(
    const float* __restrict__ W0, const float* __restrict__ W1,
    const float* __restrict__ W2, const float* __restrict__ W3,
    __hip_bfloat16* __restrict__ T0, __hip_bfloat16* __restrict__ T1,
    __hip_bfloat16* __restrict__ T2, __hip_bfloat16* __restrict__ T3) {
  const float* W = blockIdx.z == 0 ? W0 : blockIdx.z == 1 ? W1
                 : blockIdx.z == 2 ? W2 : W3;
  __hip_bfloat16* T = blockIdx.z == 0 ? T0 : blockIdx.z == 1 ? T1
                    : blockIdx.z == 2 ? T2 : T3;
  __shared__ float tile[32][33];
  int bx = blockIdx.x * 32, by = blockIdx.y * 32;
  int tx = threadIdx.x, ty = threadIdx.y;   // block (32,8)
  for (int j = 0; j < 32; j += 8)
    tile[ty + j][tx] = W[(size_t)(by + ty + j) * DMODEL + bx + tx];
  __syncthreads();
  for (int j = 0; j < 32; j += 8)
    T[(size_t)(bx + ty + j) * DMODEL + by + tx] = __float2bfloat16(tile[tx][ty + j]);
}

// 16-MFMA cluster: acc[MB..MB+3][0..3] += AF[j] x BF[n]
#define MFMA16(AF, BF, MB)                                                   \
  do {                                                                       \
    _Pragma("unroll")                                                        \
    for (int j_ = 0; j_ < 4; ++j_) {                                         \
      _Pragma("unroll")                                                      \
      for (int n_ = 0; n_ < 4; ++n_)                                         \
        acc[(MB) + j_][n_] = __builtin_amdgcn_mfma_f32_16x16x32_bf16(        \
            AF[j_], BF[n_], acc[(MB) + j_][n_], 0, 0, 0);                    \
    }                                                                        \
  } while (0)

// ---------------- GEMM: C[M][N] = A[M][K] @ Bt[N][K]^T + bias ----------------
// 256x256 tile, BK=64, 8 waves (2M x 4N), per-wave 128x64 output.
// T3+T4 faithful port: staging split into 4 K-half panel groups per tile
// (A-ks0, B-ks0, A-ks1, B-ks1; 2 gloads/thread each), one group issued per
// phase. Counted s_waitcnt vmcnt(2) at phases 1 and 3 only -- 2 groups always
// in flight, the VMEM queue never drains in the main loop. Group cover =
// 2-3 phases >= HBM latency.
// LDS layout per panel: [row][chunk 0-3] (row stride 64B), 2-bit XOR swizzle
// chunk c_l holds global chunk c_l ^ (r&3). ds_read_b128 bank-quad =
// 4*(r&1) + (l4^(lrow&3)) -> 8 lanes/quad uniform = conflict-free.
// Lane k-mapping identical to R1-R4 (global k = s*32 + l4*8 + 0..7).
// Race check: group G written at phase p targets the buffer whose last reads
// retired >=1 barrier before p (per-panel, verified).
template <bool OUT_BF16>
__global__ __launch_bounds__(512, 2) void gemm_bt_kernel(
    const __hip_bfloat16* __restrict__ A,   // [M][K]
    const __hip_bfloat16* __restrict__ Bt0, // [N][K] (= W^T)
    const __hip_bfloat16* __restrict__ Bt1,
    const __hip_bfloat16* __restrict__ Bt2,
    const float* __restrict__ bias0, const float* __restrict__ bias1,
    const float* __restrict__ bias2,
    void* __restrict__ C0, void* __restrict__ C1, void* __restrict__ C2) {
  const int mat   = blockIdx.y / NTC;
  const int ntile = blockIdx.y % NTC;
  const __hip_bfloat16* Bt = mat == 0 ? Bt0 : mat == 1 ? Bt1 : Bt2;
  const float* bias        = mat == 0 ? bias0 : mat == 1 ? bias1 : bias2;
  void* C                  = mat == 0 ? C0 : mat == 1 ? C1 : C2;

  const int bm = blockIdx.x * 256;
  const int bn = ntile * 256;

  // A: 2 bufs x 2 ks x 16KB = 64KB at 0; B: same at 65536. Total 128KB.
  __shared__ __align__(16) char SLDS[131072];

  const int tid  = threadIdx.x;
  const int lane = tid & 63;
  const int wid  = tid >> 6;            // 0..7
  const int wm   = (wid >> 2) * 128;    // wave row offset: 0,128
  const int wn   = (wid & 3) * 64;      // wave col offset: 0,64,128,192
  const int lrow = lane & 15;
  const int l4   = lane >> 4;           // 0..3

  // ---- stage source pointers: gsrc[mat][i][s], +t*128 bytes per K-tile ----
  // thread covers row r = wid*32 + i*16 + (lane>>2), chunk c_l = lane&3;
  // global chunk = 4s + (c_l ^ (r&3)).
  const int rsub  = lane >> 2;               // 0..15
  const int cswz  = (lane & 3) ^ (rsub & 3); // global chunk low bits
  const char* gsrc[2][2][2];
#pragma unroll
  for (int i = 0; i < 2; ++i) {
    const int rA = bm + wid * 32 + i * 16 + rsub;
    const int rB = bn + wid * 32 + i * 16 + rsub;
#pragma unroll
    for (int s = 0; s < 2; ++s) {
      gsrc[0][i][s] = (const char*)A  + (size_t)rA * (DMODEL * 2) + s * 64 + cswz * 16;
      gsrc[1][i][s] = (const char*)Bt + (size_t)rB * (DMODEL * 2) + s * 64 + cswz * 16;
    }
  }

  // issue one panel group (2 gloads): dst = linear 16KB panel, wave-uniform base
  auto issueGroup = [&](int M, int s, int nbuf, size_t koff) {
    char* d = SLDS + M * 65536 + nbuf * 32768 + s * 16384 + wid * 2048;
    gload16(gsrc[M][0][s] + koff, d);
    gload16(gsrc[M][1][s] + koff, d + 1024);
  };

  f32x4 acc[8][4];
#pragma unroll
  for (int i = 0; i < 8; ++i)
#pragma unroll
    for (int j = 0; j < 4; ++j) acc[i][j] = (f32x4){0.f, 0.f, 0.f, 0.f};

  // ---- read base offsets (bytes) ----
  const int swz  = ((l4 ^ (lrow & 3)) << 4);
  const int aOff = (wm + lrow) * 64 + swz;           // within A region
  const int bOff = 65536 + (wn + lrow) * 64 + swz;   // within B region

  // ---- prologue: all 4 groups of tile 0 into buf 0; wait ks0 pair ----
  issueGroup(0, 0, 0, 0);   // A-ks0
  issueGroup(1, 0, 0, 0);   // B-ks0
  issueGroup(0, 1, 0, 0);   // A-ks1
  issueGroup(1, 1, 0, 0);   // B-ks1
  asm volatile("s_waitcnt vmcnt(4)" ::: "memory");
  __builtin_amdgcn_s_barrier();

  bf16x8 aFa[4], aFb[4], aFc[4], aFd[4], bF0[4], bF1[4];
#pragma unroll
  for (int j = 0; j < 4; ++j) aFa[j] = *(const bf16x8*)(const void*)(SLDS + aOff + j * 1024);
#pragma unroll
  for (int n = 0; n < 4; ++n) bF0[n] = *(const bf16x8*)(const void*)(SLDS + bOff + n * 1024);
  __builtin_amdgcn_sched_barrier(0);

  for (int t = 0; t < NKT; ++t) {
    const int buf = t & 1, nbuf = buf ^ 1;
    const int b0 = buf << 15;
    const int n0 = nbuf << 15;
    const size_t koff = (size_t)(t + 1) * (BK * 2);
    const bool pf = (t + 1 < NKT);

    // ---------- phase 0: MFMA(ks0, m0-3); read A ks0 m4-7; issue A-ks0(t+1) ----------
    __builtin_amdgcn_s_barrier();
#pragma unroll
    for (int j = 0; j < 4; ++j)
      aFb[j] = *(const bf16x8*)(const void*)(SLDS + b0 + aOff + (4 + j) * 1024);
    if (pf) issueGroup(0, 0, nbuf, koff);
    __builtin_amdgcn_sched_barrier(0);
    __builtin_amdgcn_s_setprio(1);
    MFMA16(aFa, bF0, 0);
    __builtin_amdgcn_s_setprio(0);
    __builtin_amdgcn_sched_barrier(0);

    // ---------- phase 1: MFMA(ks0, m4-7); read A ks1 m0-3 + B ks1; issue B-ks0(t+1) ----------
    if (pf) asm volatile("s_waitcnt vmcnt(2)" ::: "memory");  // retire A-ks1,B-ks1(t)
    else    asm volatile("s_waitcnt vmcnt(0)" ::: "memory");
    __builtin_amdgcn_s_barrier();
#pragma unroll
    for (int j = 0; j < 4; ++j)
      aFc[j] = *(const bf16x8*)(const void*)(SLDS + b0 + 16384 + aOff + j * 1024);
#pragma unroll
    for (int n = 0; n < 4; ++n)
      bF1[n] = *(const bf16x8*)(const void*)(SLDS + b0 + 16384 + bOff + n * 1024);
    if (pf) issueGroup(1, 0, nbuf, koff);
    __builtin_amdgcn_sched_barrier(0);
    __builtin_amdgcn_s_setprio(1);
    MFMA16(aFb, bF0, 4);
    __builtin_amdgcn_s_setprio(0);
    __builtin_amdgcn_sched_barrier(0);

    // ---------- phase 2: MFMA(ks1, m0-3); read A ks1 m4-7; issue A-ks1(t+1) ----------
    __builtin_amdgcn_s_barrier();
#pragma unroll
    for (int j = 0; j < 4; ++j)
      aFd[j] = *(const bf16x8*)(const void*)(SLDS + b0 + 16384 + aOff + (4 + j) * 1024);
    if (pf) issueGroup(0, 1, nbuf, koff);
    __builtin_amdgcn_sched_barrier(0);
    __builtin_amdgcn_s_setprio(1);
    MFMA16(aFc, bF1, 0);
    __builtin_amdgcn_s_setprio(0);
    __builtin_amdgcn_sched_barrier(0);

    // ---------- phase 3: MFMA(ks1, m4-7); read next ks0 (A m0-3 + B); issue B-ks1(t+1) ----------
    if (pf) asm volatile("s_waitcnt vmcnt(2)" ::: "memory");  // retire A-ks0,B-ks0(t+1)
    __builtin_amdgcn_s_barrier();
    if (pf) {
#pragma unroll
      for (int j = 0; j < 4; ++j)
        aFa[j] = *(const bf16x8*)(const void*)(SLDS + n0 + aOff + j * 1024);
#pragma unroll
      for (int n = 0; n < 4; ++n)
        bF0[n] = *(const bf16x8*)(const void*)(SLDS + n0 + bOff + n * 1024);
      issueGroup(1, 1, nbuf, koff);
    }
    __builtin_amdgcn_sched_barrier(0);
    __builtin_amdgcn_s_setprio(1);
    MFMA16(aFd, bF1, 4);
    __builtin_amdgcn_s_setprio(0);
    __builtin_amdgcn_sched_barrier(0);
  }

  // ---- epilogue: C/D layout col=lane&15, row=(lane>>4)*4+r (HW-verified R1) ----
  const int rbase = l4 * 4;
#pragma unroll
  for (int mi = 0; mi < 8; ++mi) {
#pragma unroll
    for (int ni = 0; ni < 4; ++ni) {
      const int col = bn + wn + ni * 16 + lrow;
      const float b = bias[col];
#pragma unroll
      for (int r = 0; r < 4; ++r) {
        const int row = bm + wm + mi * 16 + rbase + r;
        const float val = acc[mi][ni][r] + b;
        if (OUT_BF16)
          ((__hip_bfloat16*)C)[(size_t)row * DMODEL + col] = __float2bfloat16(val);
        else
          ((float*)C)[(size_t)row * DMODEL + col] = val;
      }
    }
  }
}

// ---------------- per-position head-mixing attention ----------------
// scores[h][t] = (q[h,:] . k[t,:]) / sqrt(80) over heads (16x16), softmax
// over t, out[h][d] = sum_t p[h][t] v[t][d], * per_dim_scale[d].
// All global loads/stores vectorized bf16x8 (80 = 10 x 8, head-aligned).
__global__ __launch_bounds__(256) void attn_kernel(
    const __hip_bfloat16* __restrict__ q, const __hip_bfloat16* __restrict__ k,
    const __hip_bfloat16* __restrict__ v, const float* __restrict__ pds,
    __hip_bfloat16* __restrict__ out) {
  const size_t base = (size_t)blockIdx.x * DMODEL;
  __shared__ float qs[16][81], ks[16][81], vs[16][81];
  __shared__ float ps[16][17];
  const int tid = threadIdx.x;

  // 480 chunk loads (3 matrices x 160 bf16x8 chunks)
  for (int c = tid; c < 480; c += 256) {
    int matid = c / 160, idx = c - matid * 160;
    int h = idx / 10, d0 = (idx - h * 10) * 8;
    const __hip_bfloat16* src = matid == 0 ? q : matid == 1 ? k : v;
    union { bf16x8 v8; unsigned short u[8]; } uu;
    uu.v8 = *(const bf16x8*)(const void*)(src + base + (size_t)idx * 8);
    float* dst = (matid == 0 ? &qs[0][0] : matid == 1 ? &ks[0][0] : &vs[0][0]) +
                 h * 81 + d0;
#pragma unroll
    for (int j = 0; j < 8; ++j) dst[j] = bf2f(uu.u[j]);
  }
  __syncthreads();

  const int h = tid >> 4, t = tid & 15;
  float s = 0.f;
#pragma unroll
  for (int d = 0; d < DHEAD; ++d) s += qs[h][d] * ks[t][d];
  s *= 0.11180339887498948f;  // 1/sqrt(80)

  float m = s;
#pragma unroll
  for (int off = 8; off; off >>= 1) m = fmaxf(m, __shfl_xor(m, off, 16));
  float e = expf(s - m);
  float sum = e;
#pragma unroll
  for (int off = 8; off; off >>= 1) sum += __shfl_xor(sum, off, 16);
  ps[h][t] = e / sum;
  __syncthreads();

  // 160 output chunks, bf16x8 stores
  if (tid < 160) {
    int hh = tid / 10, d0 = (tid - hh * 10) * 8;
    union { bf16x8 v8; unsigned short u[8]; } oo;
#pragma unroll
    for (int j = 0; j < 8; ++j) {
      float o = 0.f;
#pragma unroll
      for (int tt = 0; tt < 16; ++tt) o += ps[hh][tt] * vs[tt][d0 + j];
      o *= pds[d0 + j];
      __hip_bfloat16 hb = __float2bfloat16(o);
      oo.u[j] = *(unsigned short*)&hb;
    }
    *(bf16x8*)(void*)(out + base + (size_t)tid * 8) = oo.v8;
  }
}

// ---------------- launch ----------------
extern "C" void kernel_launch(void* const* d_in, const int* in_sizes, int n_in,
                              void* d_out, int out_size, void* d_ws, size_t ws_size,
                              hipStream_t stream) {
  const float* x   = (const float*)d_in[0];
  const float* Wq  = (const float*)d_in[1];
  const float* bq  = (const float*)d_in[2];
  const float* Wk  = (const float*)d_in[3];
  const float* bk  = (const float*)d_in[4];
  const float* Wv  = (const float*)d_in[5];
  const float* bv  = (const float*)d_in[6];
  const float* Wp  = (const float*)d_in[7];
  const float* bp  = (const float*)d_in[8];
  const float* pds = (const float*)d_in[9];
  float* out = (float*)d_out;

  char* ws = (char*)d_ws;
  const size_t ACT = (size_t)M_TOT * DMODEL * 2;      // 41,943,040 B
  const size_t WT  = (size_t)DMODEL * DMODEL * 2;     //  3,276,800 B
  __hip_bfloat16* xbf = (__hip_bfloat16*)(ws);
  __hip_bfloat16* qbf = (__hip_bfloat16*)(ws + ACT);
  __hip_bfloat16* kbf = (__hip_bfloat16*)(ws + 2 * ACT);
  __hip_bfloat16* vbf = (__hip_bfloat16*)(ws + 3 * ACT);
  __hip_bfloat16* wtq = (__hip_bfloat16*)(ws + 4 * ACT);
  __hip_bfloat16* wtk = (__hip_bfloat16*)(ws + 4 * ACT + WT);
  __hip_bfloat16* wtv = (__hip_bfloat16*)(ws + 4 * ACT + 2 * WT);
  __hip_bfloat16* wtp = (__hip_bfloat16*)(ws + 4 * ACT + 3 * WT);
  __hip_bfloat16* attnbf = xbf;  // alias: x is dead after the QKV GEMM

  // 1) x -> bf16
  {
    int n4 = (M_TOT * DMODEL) / 4;  // 5,242,880
    cvt_bf16_kernel<<<n4 / 256, 256, 0, stream>>>(x, xbf, n4);
  }
  // 2) transpose+convert the 4 weight matrices
  {
    dim3 g(DMODEL / 32, DMODEL / 32, 4), b(32, 8);
    transpose_cvt_kernel<<<g, b, 0, stream>>>(Wq, Wk, Wv, Wp, wtq, wtk, wtv, wtp);
  }
  // 3) fused QKV GEMM: grid (M/256, 3*5)
  {
    dim3 g(M_TOT / 256, 3 * NTC);
    gemm_bt_kernel<true><<<g, 512, 0, stream>>>(
        xbf, wtq, wtk, wtv, bq, bk, bv, (void*)qbf, (void*)kbf, (void*)vbf);
  }
  // 4) per-position attention (+ per_dim_scale), bf16 out over xbf
  attn_kernel<<<M_TOT, 256, 0, stream>>>(qbf, kbf, vbf, pds, attnbf);
  // 5) output projection -> fp32 d_out
  {
    dim3 g(M_TOT / 256, NTC);
    gemm_bt_kernel<false><<<g, 512, 0, stream>>>(
        attnbf, wtp, wtp, wtp, bp, bp, bp, (void*)out, (void*)out, (void*)out);
  }
}

// Round 6
// 349.426 us; speedup vs baseline: 1.3697x; 1.0197x over previous
//
#include <hip/hip_runtime.h>
#include <hip/hip_bf16.h>

// Problem constants (B=8,S=2048,H=16,D=80 -> DM=1280, M=B*S=16384)
#define M_TOT   16384
#define DMODEL  1280
#define NHEAD   16
#define DHEAD   80
#define NTC     5          // 1280 / 256 column tiles per matrix
#define BK      64
#define NKT     (DMODEL / BK)   // 20 K-tiles

typedef __attribute__((ext_vector_type(8))) __bf16 bf16x8;
typedef __attribute__((ext_vector_type(4))) float  f32x4;

__device__ __forceinline__ void gload16(const void* g, void* l) {
  __builtin_amdgcn_global_load_lds(
      (const __attribute__((address_space(1))) void*)g,
      (__attribute__((address_space(3))) void*)l, 16, 0, 0);
}

__device__ __forceinline__ float bf2f(unsigned short u) {
  return __uint_as_float((unsigned)u << 16);
}

// ---------------- fp32 -> bf16 convert, vectorized ----------------
__global__ __launch_bounds__(256) void cvt_bf16_kernel(
    const float* __restrict__ x, __hip_bfloat16* __restrict__ y, int n4) {
  int i = blockIdx.x * 256 + threadIdx.x;
  if (i >= n4) return;
  float4 v = ((const float4*)x)[i];
  union { ushort4 u; __hip_bfloat16 h[4]; } o;
  o.h[0] = __float2bfloat16(v.x);
  o.h[1] = __float2bfloat16(v.y);
  o.h[2] = __float2bfloat16(v.z);
  o.h[3] = __float2bfloat16(v.w);
  ((ushort4*)y)[i] = o.u;
}

// ---------------- W [K][N] fp32  ->  Wt [N][K] bf16 ----------------
__global__ __launch_bounds__(256) void transpose_cvt_kernel(
    const float* __restrict__ W0, const float* __restrict__ W1,
    const float* __restrict__ W2, const float* __restrict__ W3,
    __hip_bfloat16* __restrict__ T0, __hip_bfloat16* __restrict__ T1,
    __hip_bfloat16* __restrict__ T2, __hip_bfloat16* __restrict__ T3) {
  const float* W = blockIdx.z == 0 ? W0 : blockIdx.z == 1 ? W1
                 : blockIdx.z == 2 ? W2 : W3;
  __hip_bfloat16* T = blockIdx.z == 0 ? T0 : blockIdx.z == 1 ? T1
                    : blockIdx.z == 2 ? T2 : T3;
  __shared__ float tile[32][33];
  int bx = blockIdx.x * 32, by = blockIdx.y * 32;
  int tx = threadIdx.x, ty = threadIdx.y;   // block (32,8)
  for (int j = 0; j < 32; j += 8)
    tile[ty + j][tx] = W[(size_t)(by + ty + j) * DMODEL + bx + tx];
  __syncthreads();
  for (int j = 0; j < 32; j += 8)
    T[(size_t)(bx + ty + j) * DMODEL + by + tx] = __float2bfloat16(tile[tx][ty + j]);
}

// 16-MFMA cluster: acc[MB..MB+3][0..3] += AF[j] x BF[n]
#define MFMA16(AF, BF, MB)                                                   \
  do {                                                                       \
    _Pragma("unroll")                                                        \
    for (int j_ = 0; j_ < 4; ++j_) {                                         \
      _Pragma("unroll")                                                      \
      for (int n_ = 0; n_ < 4; ++n_)                                         \
        acc[(MB) + j_][n_] = __builtin_amdgcn_mfma_f32_16x16x32_bf16(        \
            AF[j_], BF[n_], acc[(MB) + j_][n_], 0, 0, 0);                    \
    }                                                                        \
  } while (0)

// ---------------- GEMM: C[M][N] = A[M][K] @ Bt[N][K]^T + bias ----------------
// 256x256 tile, BK=64, 8 waves (2M x 4N), per-wave 128x64 output.
// T3+T4: staging split into 4 K-half panel groups per tile (A-ks0, B-ks0,
// A-ks1, B-ks1; 2 gloads/thread each), one group per phase, counted
// s_waitcnt vmcnt(2) at phases 1 and 3 only (queue never drains).
// LDS layout per panel: [row][chunk 0-3] (row stride 64B), 2-bit XOR swizzle
// with key (row>>1)&3  [R5 ERRATUM: key row&3 gave 2 lanes/bank-quad within
// each 8-lane hw group -> 1.5e7 conflicts. With key (row>>1)&3, quad =
// 4*(lrow&1) + (l4^((lrow>>1)&3)) covers all 8 quads per 8-lane group ->
// conflict-free (verified by enumeration for all l4 groups)].
// Lane k-mapping identical to R1-R5 (global k = s*32 + l4*8 + 0..7); the
// permutation only changes where chunks sit in LDS, so numerics unchanged.
template <bool OUT_BF16>
__global__ __launch_bounds__(512, 2) void gemm_bt_kernel(
    const __hip_bfloat16* __restrict__ A,   // [M][K]
    const __hip_bfloat16* __restrict__ Bt0, // [N][K] (= W^T)
    const __hip_bfloat16* __restrict__ Bt1,
    const __hip_bfloat16* __restrict__ Bt2,
    const float* __restrict__ bias0, const float* __restrict__ bias1,
    const float* __restrict__ bias2,
    void* __restrict__ C0, void* __restrict__ C1, void* __restrict__ C2) {
  const int mat   = blockIdx.y / NTC;
  const int ntile = blockIdx.y % NTC;
  const __hip_bfloat16* Bt = mat == 0 ? Bt0 : mat == 1 ? Bt1 : Bt2;
  const float* bias        = mat == 0 ? bias0 : mat == 1 ? bias1 : bias2;
  void* C                  = mat == 0 ? C0 : mat == 1 ? C1 : C2;

  const int bm = blockIdx.x * 256;
  const int bn = ntile * 256;

  // A: 2 bufs x 2 ks x 16KB = 64KB at 0; B: same at 65536. Total 128KB.
  __shared__ __align__(16) char SLDS[131072];

  const int tid  = threadIdx.x;
  const int lane = tid & 63;
  const int wid  = tid >> 6;            // 0..7
  const int wm   = (wid >> 2) * 128;    // wave row offset: 0,128
  const int wn   = (wid & 3) * 64;      // wave col offset: 0,64,128,192
  const int lrow = lane & 15;
  const int l4   = lane >> 4;           // 0..3

  // ---- stage source pointers: gsrc[mat][i][s], +t*128 bytes per K-tile ----
  // thread covers row r = wid*32 + i*16 + (lane>>2), local chunk c_l = lane&3;
  // stored global chunk = 4s + (c_l ^ ((r>>1)&3)).
  const int rsub  = lane >> 2;                        // 0..15
  const int cswz  = (lane & 3) ^ ((rsub >> 1) & 3);   // global chunk low bits
  const char* gsrc[2][2][2];
#pragma unroll
  for (int i = 0; i < 2; ++i) {
    const int rA = bm + wid * 32 + i * 16 + rsub;
    const int rB = bn + wid * 32 + i * 16 + rsub;
#pragma unroll
    for (int s = 0; s < 2; ++s) {
      gsrc[0][i][s] = (const char*)A  + (size_t)rA * (DMODEL * 2) + s * 64 + cswz * 16;
      gsrc[1][i][s] = (const char*)Bt + (size_t)rB * (DMODEL * 2) + s * 64 + cswz * 16;
    }
  }

  // issue one panel group (2 gloads): dst = linear 16KB panel, wave-uniform base
  auto issueGroup = [&](int M, int s, int nbuf, size_t koff) {
    char* d = SLDS + M * 65536 + nbuf * 32768 + s * 16384 + wid * 2048;
    gload16(gsrc[M][0][s] + koff, d);
    gload16(gsrc[M][1][s] + koff, d + 1024);
  };

  f32x4 acc[8][4];
#pragma unroll
  for (int i = 0; i < 8; ++i)
#pragma unroll
    for (int j = 0; j < 4; ++j) acc[i][j] = (f32x4){0.f, 0.f, 0.f, 0.f};

  // ---- read base offsets (bytes): lane reads local chunk l4^((lrow>>1)&3) ----
  const int swz  = ((l4 ^ ((lrow >> 1) & 3)) << 4);
  const int aOff = (wm + lrow) * 64 + swz;           // within A region
  const int bOff = 65536 + (wn + lrow) * 64 + swz;   // within B region

  // ---- prologue: all 4 groups of tile 0 into buf 0; wait ks0 pair ----
  issueGroup(0, 0, 0, 0);   // A-ks0
  issueGroup(1, 0, 0, 0);   // B-ks0
  issueGroup(0, 1, 0, 0);   // A-ks1
  issueGroup(1, 1, 0, 0);   // B-ks1
  asm volatile("s_waitcnt vmcnt(4)" ::: "memory");
  __builtin_amdgcn_s_barrier();

  bf16x8 aFa[4], aFb[4], aFc[4], aFd[4], bF0[4], bF1[4];
#pragma unroll
  for (int j = 0; j < 4; ++j) aFa[j] = *(const bf16x8*)(const void*)(SLDS + aOff + j * 1024);
#pragma unroll
  for (int n = 0; n < 4; ++n) bF0[n] = *(const bf16x8*)(const void*)(SLDS + bOff + n * 1024);
  __builtin_amdgcn_sched_barrier(0);

  for (int t = 0; t < NKT; ++t) {
    const int buf = t & 1, nbuf = buf ^ 1;
    const int b0 = buf << 15;
    const int n0 = nbuf << 15;
    const size_t koff = (size_t)(t + 1) * (BK * 2);
    const bool pf = (t + 1 < NKT);

    // ---------- phase 0: MFMA(ks0, m0-3); read A ks0 m4-7; issue A-ks0(t+1) ----------
    __builtin_amdgcn_s_barrier();
#pragma unroll
    for (int j = 0; j < 4; ++j)
      aFb[j] = *(const bf16x8*)(const void*)(SLDS + b0 + aOff + (4 + j) * 1024);
    if (pf) issueGroup(0, 0, nbuf, koff);
    __builtin_amdgcn_sched_barrier(0);
    __builtin_amdgcn_s_setprio(1);
    MFMA16(aFa, bF0, 0);
    __builtin_amdgcn_s_setprio(0);
    __builtin_amdgcn_sched_barrier(0);

    // ---------- phase 1: MFMA(ks0, m4-7); read A ks1 m0-3 + B ks1; issue B-ks0(t+1) ----------
    if (pf) asm volatile("s_waitcnt vmcnt(2)" ::: "memory");  // retire A-ks1,B-ks1(t)
    else    asm volatile("s_waitcnt vmcnt(0)" ::: "memory");
    __builtin_amdgcn_s_barrier();
#pragma unroll
    for (int j = 0; j < 4; ++j)
      aFc[j] = *(const bf16x8*)(const void*)(SLDS + b0 + 16384 + aOff + j * 1024);
#pragma unroll
    for (int n = 0; n < 4; ++n)
      bF1[n] = *(const bf16x8*)(const void*)(SLDS + b0 + 16384 + bOff + n * 1024);
    if (pf) issueGroup(1, 0, nbuf, koff);
    __builtin_amdgcn_sched_barrier(0);
    __builtin_amdgcn_s_setprio(1);
    MFMA16(aFb, bF0, 4);
    __builtin_amdgcn_s_setprio(0);
    __builtin_amdgcn_sched_barrier(0);

    // ---------- phase 2: MFMA(ks1, m0-3); read A ks1 m4-7; issue A-ks1(t+1) ----------
    __builtin_amdgcn_s_barrier();
#pragma unroll
    for (int j = 0; j < 4; ++j)
      aFd[j] = *(const bf16x8*)(const void*)(SLDS + b0 + 16384 + aOff + (4 + j) * 1024);
    if (pf) issueGroup(0, 1, nbuf, koff);
    __builtin_amdgcn_sched_barrier(0);
    __builtin_amdgcn_s_setprio(1);
    MFMA16(aFc, bF1, 0);
    __builtin_amdgcn_s_setprio(0);
    __builtin_amdgcn_sched_barrier(0);

    // ---------- phase 3: MFMA(ks1, m4-7); read next ks0 (A m0-3 + B); issue B-ks1(t+1) ----------
    if (pf) asm volatile("s_waitcnt vmcnt(2)" ::: "memory");  // retire A-ks0,B-ks0(t+1)
    __builtin_amdgcn_s_barrier();
    if (pf) {
#pragma unroll
      for (int j = 0; j < 4; ++j)
        aFa[j] = *(const bf16x8*)(const void*)(SLDS + n0 + aOff + j * 1024);
#pragma unroll
      for (int n = 0; n < 4; ++n)
        bF0[n] = *(const bf16x8*)(const void*)(SLDS + n0 + bOff + n * 1024);
      issueGroup(1, 1, nbuf, koff);
    }
    __builtin_amdgcn_sched_barrier(0);
    __builtin_amdgcn_s_setprio(1);
    MFMA16(aFd, bF1, 4);
    __builtin_amdgcn_s_setprio(0);
    __builtin_amdgcn_sched_barrier(0);
  }

  // ---- epilogue: C/D layout col=lane&15, row=(lane>>4)*4+r (HW-verified R1) ----
  const int rbase = l4 * 4;
#pragma unroll
  for (int mi = 0; mi < 8; ++mi) {
#pragma unroll
    for (int ni = 0; ni < 4; ++ni) {
      const int col = bn + wn + ni * 16 + lrow;
      const float b = bias[col];
#pragma unroll
      for (int r = 0; r < 4; ++r) {
        const int row = bm + wm + mi * 16 + rbase + r;
        const float val = acc[mi][ni][r] + b;
        if (OUT_BF16)
          ((__hip_bfloat16*)C)[(size_t)row * DMODEL + col] = __float2bfloat16(val);
        else
          ((float*)C)[(size_t)row * DMODEL + col] = val;
      }
    }
  }
}

// ---------------- per-position head-mixing attention ----------------
// scores[h][t] = (q[h,:] . k[t,:]) / sqrt(80) over heads (16x16), softmax
// over t, out[h][d] = sum_t p[h][t] v[t][d], * per_dim_scale[d].
// All global loads/stores vectorized bf16x8 (80 = 10 x 8, head-aligned).
__global__ __launch_bounds__(256) void attn_kernel(
    const __hip_bfloat16* __restrict__ q, const __hip_bfloat16* __restrict__ k,
    const __hip_bfloat16* __restrict__ v, const float* __restrict__ pds,
    __hip_bfloat16* __restrict__ out) {
  const size_t base = (size_t)blockIdx.x * DMODEL;
  __shared__ float qs[16][81], ks[16][81], vs[16][81];
  __shared__ float ps[16][17];
  const int tid = threadIdx.x;

  // 480 chunk loads (3 matrices x 160 bf16x8 chunks)
  for (int c = tid; c < 480; c += 256) {
    int matid = c / 160, idx = c - matid * 160;
    int h = idx / 10, d0 = (idx - h * 10) * 8;
    const __hip_bfloat16* src = matid == 0 ? q : matid == 1 ? k : v;
    union { bf16x8 v8; unsigned short u[8]; } uu;
    uu.v8 = *(const bf16x8*)(const void*)(src + base + (size_t)idx * 8);
    float* dst = (matid == 0 ? &qs[0][0] : matid == 1 ? &ks[0][0] : &vs[0][0]) +
                 h * 81 + d0;
#pragma unroll
    for (int j = 0; j < 8; ++j) dst[j] = bf2f(uu.u[j]);
  }
  __syncthreads();

  const int h = tid >> 4, t = tid & 15;
  float s = 0.f;
#pragma unroll
  for (int d = 0; d < DHEAD; ++d) s += qs[h][d] * ks[t][d];
  s *= 0.11180339887498948f;  // 1/sqrt(80)

  float m = s;
#pragma unroll
  for (int off = 8; off; off >>= 1) m = fmaxf(m, __shfl_xor(m, off, 16));
  float e = expf(s - m);
  float sum = e;
#pragma unroll
  for (int off = 8; off; off >>= 1) sum += __shfl_xor(sum, off, 16);
  ps[h][t] = e / sum;
  __syncthreads();

  // 160 output chunks, bf16x8 stores
  if (tid < 160) {
    int hh = tid / 10, d0 = (tid - hh * 10) * 8;
    union { bf16x8 v8; unsigned short u[8]; } oo;
#pragma unroll
    for (int j = 0; j < 8; ++j) {
      float o = 0.f;
#pragma unroll
      for (int tt = 0; tt < 16; ++tt) o += ps[hh][tt] * vs[tt][d0 + j];
      o *= pds[d0 + j];
      __hip_bfloat16 hb = __float2bfloat16(o);
      oo.u[j] = *(unsigned short*)&hb;
    }
    *(bf16x8*)(void*)(out + base + (size_t)tid * 8) = oo.v8;
  }
}

// ---------------- launch ----------------
extern "C" void kernel_launch(void* const* d_in, const int* in_sizes, int n_in,
                              void* d_out, int out_size, void* d_ws, size_t ws_size,
                              hipStream_t stream) {
  const float* x   = (const float*)d_in[0];
  const float* Wq  = (const float*)d_in[1];
  const float* bq  = (const float*)d_in[2];
  const float* Wk  = (const float*)d_in[3];
  const float* bk  = (const float*)d_in[4];
  const float* Wv  = (const float*)d_in[5];
  const float* bv  = (const float*)d_in[6];
  const float* Wp  = (const float*)d_in[7];
  const float* bp  = (const float*)d_in[8];
  const float* pds = (const float*)d_in[9];
  float* out = (float*)d_out;

  char* ws = (char*)d_ws;
  const size_t ACT = (size_t)M_TOT * DMODEL * 2;      // 41,943,040 B
  const size_t WT  = (size_t)DMODEL * DMODEL * 2;     //  3,276,800 B
  __hip_bfloat16* xbf = (__hip_bfloat16*)(ws);
  __hip_bfloat16* qbf = (__hip_bfloat16*)(ws + ACT);
  __hip_bfloat16* kbf = (__hip_bfloat16*)(ws + 2 * ACT);
  __hip_bfloat16* vbf = (__hip_bfloat16*)(ws + 3 * ACT);
  __hip_bfloat16* wtq = (__hip_bfloat16*)(ws + 4 * ACT);
  __hip_bfloat16* wtk = (__hip_bfloat16*)(ws + 4 * ACT + WT);
  __hip_bfloat16* wtv = (__hip_bfloat16*)(ws + 4 * ACT + 2 * WT);
  __hip_bfloat16* wtp = (__hip_bfloat16*)(ws + 4 * ACT + 3 * WT);
  __hip_bfloat16* attnbf = xbf;  // alias: x is dead after the QKV GEMM

  // 1) x -> bf16
  {
    int n4 = (M_TOT * DMODEL) / 4;  // 5,242,880
    cvt_bf16_kernel<<<n4 / 256, 256, 0, stream>>>(x, xbf, n4);
  }
  // 2) transpose+convert the 4 weight matrices
  {
    dim3 g(DMODEL / 32, DMODEL / 32, 4), b(32, 8);
    transpose_cvt_kernel<<<g, b, 0, stream>>>(Wq, Wk, Wv, Wp, wtq, wtk, wtv, wtp);
  }
  // 3) fused QKV GEMM: grid (M/256, 3*5)
  {
    dim3 g(M_TOT / 256, 3 * NTC);
    gemm_bt_kernel<true><<<g, 512, 0, stream>>>(
        xbf, wtq, wtk, wtv, bq, bk, bv, (void*)qbf, (void*)kbf, (void*)vbf);
  }
  // 4) per-position attention (+ per_dim_scale), bf16 out over xbf
  attn_kernel<<<M_TOT, 256, 0, stream>>>(qbf, kbf, vbf, pds, attnbf);
  // 5) output projection -> fp32 d_out
  {
    dim3 g(M_TOT / 256, NTC);
    gemm_bt_kernel<false><<<g, 512, 0, stream>>>(
        attnbf, wtp, wtp, wtp, bp, bp, bp, (void*)out, (void*)out, (void*)out);
  }
}

// Round 7
// 316.693 us; speedup vs baseline: 1.5112x; 1.1034x over previous
//
#include <hip/hip_runtime.h>
#include <hip/hip_bf16.h>

// Problem constants (B=8,S=2048,H=16,D=80 -> DM=1280, M=B*S=16384)
#define M_TOT   16384
#define DMODEL  1280
#define NHEAD   16
#define DHEAD   80
#define NTC     5          // 1280 / 256 column tiles per matrix
#define BK      64
#define NKT     (DMODEL / BK)   // 20 K-tiles

typedef __attribute__((ext_vector_type(8))) __bf16 bf16x8;
typedef __attribute__((ext_vector_type(4))) float  f32x4;

__device__ __forceinline__ void gload16(const void* g, void* l) {
  __builtin_amdgcn_global_load_lds(
      (const __attribute__((address_space(1))) void*)g,
      (__attribute__((address_space(3))) void*)l, 16, 0, 0);
}

__device__ __forceinline__ float bf2f(unsigned short u) {
  return __uint_as_float((unsigned)u << 16);
}

// ---------------- fp32 -> bf16 convert, vectorized ----------------
__global__ __launch_bounds__(256) void cvt_bf16_kernel(
    const float* __restrict__ x, __hip_bfloat16* __restrict__ y, int n4) {
  int i = blockIdx.x * 256 + threadIdx.x;
  if (i >= n4) return;
  float4 v = ((const float4*)x)[i];
  union { ushort4 u; __hip_bfloat16 h[4]; } o;
  o.h[0] = __float2bfloat16(v.x);
  o.h[1] = __float2bfloat16(v.y);
  o.h[2] = __float2bfloat16(v.z);
  o.h[3] = __float2bfloat16(v.w);
  ((ushort4*)y)[i] = o.u;
}

// ---------------- W [K][N] fp32  ->  Wt [N][K] bf16 ----------------
__global__ __launch_bounds__(256) void transpose_cvt_kernel(
    const float* __restrict__ W0, const float* __restrict__ W1,
    const float* __restrict__ W2, const float* __restrict__ W3,
    __hip_bfloat16* __restrict__ T0, __hip_bfloat16* __restrict__ T1,
    __hip_bfloat16* __restrict__ T2, __hip_bfloat16* __restrict__ T3) {
  const float* W = blockIdx.z == 0 ? W0 : blockIdx.z == 1 ? W1
                 : blockIdx.z == 2 ? W2 : W3;
  __hip_bfloat16* T = blockIdx.z == 0 ? T0 : blockIdx.z == 1 ? T1
                    : blockIdx.z == 2 ? T2 : T3;
  __shared__ float tile[32][33];
  int bx = blockIdx.x * 32, by = blockIdx.y * 32;
  int tx = threadIdx.x, ty = threadIdx.y;   // block (32,8)
  for (int j = 0; j < 32; j += 8)
    tile[ty + j][tx] = W[(size_t)(by + ty + j) * DMODEL + bx + tx];
  __syncthreads();
  for (int j = 0; j < 32; j += 8)
    T[(size_t)(bx + ty + j) * DMODEL + by + tx] = __float2bfloat16(tile[tx][ty + j]);
}

// 16-MFMA cluster: acc[MB..MB+3][0..3] += AF[j] x BF[n]
#define MFMA16(AF, BF, MB)                                                   \
  do {                                                                       \
    _Pragma("unroll")                                                        \
    for (int j_ = 0; j_ < 4; ++j_) {                                         \
      _Pragma("unroll")                                                      \
      for (int n_ = 0; n_ < 4; ++n_)                                         \
        acc[(MB) + j_][n_] = __builtin_amdgcn_mfma_f32_16x16x32_bf16(        \
            AF[j_], BF[n_], acc[(MB) + j_][n_], 0, 0, 0);                    \
    }                                                                        \
  } while (0)

// ---------------- QKV GEMM (frozen from R6): 256x256, 8 waves ----------------
template <bool OUT_BF16>
__global__ __launch_bounds__(512, 2) void gemm_bt_kernel(
    const __hip_bfloat16* __restrict__ A,   // [M][K]
    const __hip_bfloat16* __restrict__ Bt0, // [N][K] (= W^T)
    const __hip_bfloat16* __restrict__ Bt1,
    const __hip_bfloat16* __restrict__ Bt2,
    const float* __restrict__ bias0, const float* __restrict__ bias1,
    const float* __restrict__ bias2,
    void* __restrict__ C0, void* __restrict__ C1, void* __restrict__ C2) {
  const int mat   = blockIdx.y / NTC;
  const int ntile = blockIdx.y % NTC;
  const __hip_bfloat16* Bt = mat == 0 ? Bt0 : mat == 1 ? Bt1 : Bt2;
  const float* bias        = mat == 0 ? bias0 : mat == 1 ? bias1 : bias2;
  void* C                  = mat == 0 ? C0 : mat == 1 ? C1 : C2;

  const int bm = blockIdx.x * 256;
  const int bn = ntile * 256;

  // A: 2 bufs x 2 ks x 16KB = 64KB at 0; B: same at 65536. Total 128KB.
  __shared__ __align__(16) char SLDS[131072];

  const int tid  = threadIdx.x;
  const int lane = tid & 63;
  const int wid  = tid >> 6;            // 0..7
  const int wm   = (wid >> 2) * 128;    // wave row offset: 0,128
  const int wn   = (wid & 3) * 64;      // wave col offset: 0,64,128,192
  const int lrow = lane & 15;
  const int l4   = lane >> 4;           // 0..3

  const int rsub  = lane >> 2;                        // 0..15
  const int cswz  = (lane & 3) ^ ((rsub >> 1) & 3);   // global chunk low bits
  const char* gsrc[2][2][2];
#pragma unroll
  for (int i = 0; i < 2; ++i) {
    const int rA = bm + wid * 32 + i * 16 + rsub;
    const int rB = bn + wid * 32 + i * 16 + rsub;
#pragma unroll
    for (int s = 0; s < 2; ++s) {
      gsrc[0][i][s] = (const char*)A  + (size_t)rA * (DMODEL * 2) + s * 64 + cswz * 16;
      gsrc[1][i][s] = (const char*)Bt + (size_t)rB * (DMODEL * 2) + s * 64 + cswz * 16;
    }
  }

  auto issueGroup = [&](int M, int s, int nbuf, size_t koff) {
    char* d = SLDS + M * 65536 + nbuf * 32768 + s * 16384 + wid * 2048;
    gload16(gsrc[M][0][s] + koff, d);
    gload16(gsrc[M][1][s] + koff, d + 1024);
  };

  f32x4 acc[8][4];
#pragma unroll
  for (int i = 0; i < 8; ++i)
#pragma unroll
    for (int j = 0; j < 4; ++j) acc[i][j] = (f32x4){0.f, 0.f, 0.f, 0.f};

  const int swz  = ((l4 ^ ((lrow >> 1) & 3)) << 4);
  const int aOff = (wm + lrow) * 64 + swz;           // within A region
  const int bOff = 65536 + (wn + lrow) * 64 + swz;   // within B region

  issueGroup(0, 0, 0, 0);   // A-ks0
  issueGroup(1, 0, 0, 0);   // B-ks0
  issueGroup(0, 1, 0, 0);   // A-ks1
  issueGroup(1, 1, 0, 0);   // B-ks1
  asm volatile("s_waitcnt vmcnt(4)" ::: "memory");
  __builtin_amdgcn_s_barrier();

  bf16x8 aFa[4], aFb[4], aFc[4], aFd[4], bF0[4], bF1[4];
#pragma unroll
  for (int j = 0; j < 4; ++j) aFa[j] = *(const bf16x8*)(const void*)(SLDS + aOff + j * 1024);
#pragma unroll
  for (int n = 0; n < 4; ++n) bF0[n] = *(const bf16x8*)(const void*)(SLDS + bOff + n * 1024);
  __builtin_amdgcn_sched_barrier(0);

  for (int t = 0; t < NKT; ++t) {
    const int buf = t & 1, nbuf = buf ^ 1;
    const int b0 = buf << 15;
    const int n0 = nbuf << 15;
    const size_t koff = (size_t)(t + 1) * (BK * 2);
    const bool pf = (t + 1 < NKT);

    // ---------- phase 0 ----------
    __builtin_amdgcn_s_barrier();
#pragma unroll
    for (int j = 0; j < 4; ++j)
      aFb[j] = *(const bf16x8*)(const void*)(SLDS + b0 + aOff + (4 + j) * 1024);
    if (pf) issueGroup(0, 0, nbuf, koff);
    __builtin_amdgcn_sched_barrier(0);
    __builtin_amdgcn_s_setprio(1);
    MFMA16(aFa, bF0, 0);
    __builtin_amdgcn_s_setprio(0);
    __builtin_amdgcn_sched_barrier(0);

    // ---------- phase 1 ----------
    if (pf) asm volatile("s_waitcnt vmcnt(2)" ::: "memory");
    else    asm volatile("s_waitcnt vmcnt(0)" ::: "memory");
    __builtin_amdgcn_s_barrier();
#pragma unroll
    for (int j = 0; j < 4; ++j)
      aFc[j] = *(const bf16x8*)(const void*)(SLDS + b0 + 16384 + aOff + j * 1024);
#pragma unroll
    for (int n = 0; n < 4; ++n)
      bF1[n] = *(const bf16x8*)(const void*)(SLDS + b0 + 16384 + bOff + n * 1024);
    if (pf) issueGroup(1, 0, nbuf, koff);
    __builtin_amdgcn_sched_barrier(0);
    __builtin_amdgcn_s_setprio(1);
    MFMA16(aFb, bF0, 4);
    __builtin_amdgcn_s_setprio(0);
    __builtin_amdgcn_sched_barrier(0);

    // ---------- phase 2 ----------
    __builtin_amdgcn_s_barrier();
#pragma unroll
    for (int j = 0; j < 4; ++j)
      aFd[j] = *(const bf16x8*)(const void*)(SLDS + b0 + 16384 + aOff + (4 + j) * 1024);
    if (pf) issueGroup(0, 1, nbuf, koff);
    __builtin_amdgcn_sched_barrier(0);
    __builtin_amdgcn_s_setprio(1);
    MFMA16(aFc, bF1, 0);
    __builtin_amdgcn_s_setprio(0);
    __builtin_amdgcn_sched_barrier(0);

    // ---------- phase 3 ----------
    if (pf) asm volatile("s_waitcnt vmcnt(2)" ::: "memory");
    __builtin_amdgcn_s_barrier();
    if (pf) {
#pragma unroll
      for (int j = 0; j < 4; ++j)
        aFa[j] = *(const bf16x8*)(const void*)(SLDS + n0 + aOff + j * 1024);
#pragma unroll
      for (int n = 0; n < 4; ++n)
        bF0[n] = *(const bf16x8*)(const void*)(SLDS + n0 + bOff + n * 1024);
      issueGroup(1, 1, nbuf, koff);
    }
    __builtin_amdgcn_sched_barrier(0);
    __builtin_amdgcn_s_setprio(1);
    MFMA16(aFd, bF1, 4);
    __builtin_amdgcn_s_setprio(0);
    __builtin_amdgcn_sched_barrier(0);
  }

  const int rbase = l4 * 4;
#pragma unroll
  for (int mi = 0; mi < 8; ++mi) {
#pragma unroll
    for (int ni = 0; ni < 4; ++ni) {
      const int col = bn + wn + ni * 16 + lrow;
      const float b = bias[col];
#pragma unroll
      for (int r = 0; r < 4; ++r) {
        const int row = bm + wm + mi * 16 + rbase + r;
        const float val = acc[mi][ni][r] + b;
        if (OUT_BF16)
          ((__hip_bfloat16*)C)[(size_t)row * DMODEL + col] = __float2bfloat16(val);
        else
          ((float*)C)[(size_t)row * DMODEL + col] = val;
      }
    }
  }
}

// ---------------- proj GEMM: 128x128 tile, 4 waves, 2 blocks/CU ----------------
// R6 post-mortem: proj at 256x256 had grid=320 blocks @ 1 block/CU -> 256+64
// makespan, 62% CU utilization. This variant: 64KB LDS -> 2 blocks/CU,
// grid 128x10=1280 -> ~95% utilization + cross-block stall overlap.
// 2 phases/K-tile (ks0, ks1), counted vmcnt(4) at each phase start (A-ks/B-ks
// pair of NEXT tile always in flight; cover = 2 phases). Same swizzle scheme
// as QKV (key (row>>1)&3), panels 128 rows x 64B.
__global__ __launch_bounds__(256, 2) void gemm_bt128_kernel(
    const __hip_bfloat16* __restrict__ A,   // [M][K]
    const __hip_bfloat16* __restrict__ Bt,  // [N][K]
    const float* __restrict__ bias,
    float* __restrict__ C) {
  const int bm = blockIdx.x * 128;
  const int bn = blockIdx.y * 128;

  // A: 2 bufs x 2 ks x 8KB = 32KB at 0; B: same at 32768. Total 64KB.
  __shared__ __align__(16) char SLDS[65536];

  const int tid  = threadIdx.x;
  const int lane = tid & 63;
  const int wid  = tid >> 6;            // 0..3
  const int wm   = (wid >> 1) * 64;     // wave row offset: 0,64
  const int wn   = (wid & 1) * 64;      // wave col offset: 0,64
  const int lrow = lane & 15;
  const int l4   = lane >> 4;

  const int rsub  = lane >> 2;
  const int cswz  = (lane & 3) ^ ((rsub >> 1) & 3);
  const char* gsrc[2][2][2];
#pragma unroll
  for (int i = 0; i < 2; ++i) {
    const int rA = bm + wid * 32 + i * 16 + rsub;
    const int rB = bn + wid * 32 + i * 16 + rsub;
#pragma unroll
    for (int s = 0; s < 2; ++s) {
      gsrc[0][i][s] = (const char*)A  + (size_t)rA * (DMODEL * 2) + s * 64 + cswz * 16;
      gsrc[1][i][s] = (const char*)Bt + (size_t)rB * (DMODEL * 2) + s * 64 + cswz * 16;
    }
  }

  // one panel group (2 gloads): panel = 8KB, wave covers rows wid*32..+31
  auto issueGroup = [&](int M, int s, int nbuf, size_t koff) {
    char* d = SLDS + M * 32768 + nbuf * 16384 + s * 8192 + wid * 2048;
    gload16(gsrc[M][0][s] + koff, d);
    gload16(gsrc[M][1][s] + koff, d + 1024);
  };

  f32x4 acc[4][4];
#pragma unroll
  for (int i = 0; i < 4; ++i)
#pragma unroll
    for (int j = 0; j < 4; ++j) acc[i][j] = (f32x4){0.f, 0.f, 0.f, 0.f};

  const int swz  = ((l4 ^ ((lrow >> 1) & 3)) << 4);
  const int aOff = (wm + lrow) * 64 + swz;
  const int bOff = 32768 + (wn + lrow) * 64 + swz;

  // prologue: all 4 groups of tile 0 into buf 0
  issueGroup(0, 0, 0, 0);   // A-ks0 (2 loads)
  issueGroup(1, 0, 0, 0);   // B-ks0
  issueGroup(0, 1, 0, 0);   // A-ks1
  issueGroup(1, 1, 0, 0);   // B-ks1

  for (int t = 0; t < NKT; ++t) {
    const int buf = t & 1, nbuf = buf ^ 1;
    const int b0 = buf << 14;            // 16KB per buf within each region
    const size_t koff = (size_t)(t + 1) * (BK * 2);
    const bool pf = (t + 1 < NKT);

    // ---------- phase 0: ks0 ----------
    asm volatile("s_waitcnt vmcnt(4)" ::: "memory");  // A-ks0,B-ks0(t) landed
    __builtin_amdgcn_s_barrier();
    bf16x8 aF[4], bF[4];
#pragma unroll
    for (int j = 0; j < 4; ++j)
      aF[j] = *(const bf16x8*)(const void*)(SLDS + b0 + aOff + j * 1024);
#pragma unroll
    for (int n = 0; n < 4; ++n)
      bF[n] = *(const bf16x8*)(const void*)(SLDS + b0 + bOff + n * 1024);
    if (pf) { issueGroup(0, 0, nbuf, koff); issueGroup(1, 0, nbuf, koff); }
    __builtin_amdgcn_sched_barrier(0);
    __builtin_amdgcn_s_setprio(1);
    MFMA16(aF, bF, 0);
    __builtin_amdgcn_s_setprio(0);
    __builtin_amdgcn_sched_barrier(0);

    // ---------- phase 1: ks1 ----------
    if (pf) asm volatile("s_waitcnt vmcnt(4)" ::: "memory");  // A-ks1,B-ks1(t)
    else    asm volatile("s_waitcnt vmcnt(0)" ::: "memory");
    __builtin_amdgcn_s_barrier();
#pragma unroll
    for (int j = 0; j < 4; ++j)
      aF[j] = *(const bf16x8*)(const void*)(SLDS + b0 + 8192 + aOff + j * 1024);
#pragma unroll
    for (int n = 0; n < 4; ++n)
      bF[n] = *(const bf16x8*)(const void*)(SLDS + b0 + 8192 + bOff + n * 1024);
    if (pf) { issueGroup(0, 1, nbuf, koff); issueGroup(1, 1, nbuf, koff); }
    __builtin_amdgcn_sched_barrier(0);
    __builtin_amdgcn_s_setprio(1);
    MFMA16(aF, bF, 0);
    __builtin_amdgcn_s_setprio(0);
    __builtin_amdgcn_sched_barrier(0);
  }

  const int rbase = l4 * 4;
#pragma unroll
  for (int mi = 0; mi < 4; ++mi) {
#pragma unroll
    for (int ni = 0; ni < 4; ++ni) {
      const int col = bn + wn + ni * 16 + lrow;
      const float b = bias[col];
#pragma unroll
      for (int r = 0; r < 4; ++r) {
        const int row = bm + wm + mi * 16 + rbase + r;
        C[(size_t)row * DMODEL + col] = acc[mi][ni][r] + b;
      }
    }
  }
}

// ---------------- per-position head-mixing attention ----------------
// scores[h][t] = (q[h,:] . k[t,:]) / sqrt(80) over heads (16x16), softmax
// over t, out[h][d] = sum_t p[h][t] v[t][d], * per_dim_scale[d].
// Loads vectorized bf16x8; PV balanced over all 256 threads (5 outputs each,
// contiguous 10B stores) [R6: 160/256 threads was a 37% PV imbalance].
__global__ __launch_bounds__(256) void attn_kernel(
    const __hip_bfloat16* __restrict__ q, const __hip_bfloat16* __restrict__ k,
    const __hip_bfloat16* __restrict__ v, const float* __restrict__ pds,
    __hip_bfloat16* __restrict__ out) {
  const size_t base = (size_t)blockIdx.x * DMODEL;
  __shared__ float qs[16][81], ks[16][81], vs[16][81];
  __shared__ float ps[16][17];
  const int tid = threadIdx.x;

  // 480 chunk loads (3 matrices x 160 bf16x8 chunks)
  for (int c = tid; c < 480; c += 256) {
    int matid = c / 160, idx = c - matid * 160;
    int h = idx / 10, d0 = (idx - h * 10) * 8;
    const __hip_bfloat16* src = matid == 0 ? q : matid == 1 ? k : v;
    union { bf16x8 v8; unsigned short u[8]; } uu;
    uu.v8 = *(const bf16x8*)(const void*)(src + base + (size_t)idx * 8);
    float* dst = (matid == 0 ? &qs[0][0] : matid == 1 ? &ks[0][0] : &vs[0][0]) +
                 h * 81 + d0;
#pragma unroll
    for (int j = 0; j < 8; ++j) dst[j] = bf2f(uu.u[j]);
  }
  __syncthreads();

  const int h = tid >> 4, t = tid & 15;
  float s = 0.f;
#pragma unroll
  for (int d = 0; d < DHEAD; ++d) s += qs[h][d] * ks[t][d];
  s *= 0.11180339887498948f;  // 1/sqrt(80)

  float m = s;
#pragma unroll
  for (int off = 8; off; off >>= 1) m = fmaxf(m, __shfl_xor(m, off, 16));
  float e = expf(s - m);
  float sum = e;
#pragma unroll
  for (int off = 8; off; off >>= 1) sum += __shfl_xor(sum, off, 16);
  ps[h][t] = e / sum;
  __syncthreads();

  // PV: 256 threads x 5 outputs (head hh = tid>>4, d = (tid&15)*5 .. +4)
  {
    const int hh   = tid >> 4;
    const int dloc = (tid & 15) * 5;
    float o[5];
#pragma unroll
    for (int j = 0; j < 5; ++j) o[j] = 0.f;
#pragma unroll
    for (int tt = 0; tt < 16; ++tt) {
      const float p = ps[hh][tt];
#pragma unroll
      for (int j = 0; j < 5; ++j) o[j] += p * vs[tt][dloc + j];
    }
    __hip_bfloat16* ob = out + base + (size_t)hh * DHEAD + dloc;
#pragma unroll
    for (int j = 0; j < 5; ++j) ob[j] = __float2bfloat16(o[j] * pds[dloc + j]);
  }
}

// ---------------- launch ----------------
extern "C" void kernel_launch(void* const* d_in, const int* in_sizes, int n_in,
                              void* d_out, int out_size, void* d_ws, size_t ws_size,
                              hipStream_t stream) {
  const float* x   = (const float*)d_in[0];
  const float* Wq  = (const float*)d_in[1];
  const float* bq  = (const float*)d_in[2];
  const float* Wk  = (const float*)d_in[3];
  const float* bk  = (const float*)d_in[4];
  const float* Wv  = (const float*)d_in[5];
  const float* bv  = (const float*)d_in[6];
  const float* Wp  = (const float*)d_in[7];
  const float* bp  = (const float*)d_in[8];
  const float* pds = (const float*)d_in[9];
  float* out = (float*)d_out;

  char* ws = (char*)d_ws;
  const size_t ACT = (size_t)M_TOT * DMODEL * 2;      // 41,943,040 B
  const size_t WT  = (size_t)DMODEL * DMODEL * 2;     //  3,276,800 B
  __hip_bfloat16* xbf = (__hip_bfloat16*)(ws);
  __hip_bfloat16* qbf = (__hip_bfloat16*)(ws + ACT);
  __hip_bfloat16* kbf = (__hip_bfloat16*)(ws + 2 * ACT);
  __hip_bfloat16* vbf = (__hip_bfloat16*)(ws + 3 * ACT);
  __hip_bfloat16* wtq = (__hip_bfloat16*)(ws + 4 * ACT);
  __hip_bfloat16* wtk = (__hip_bfloat16*)(ws + 4 * ACT + WT);
  __hip_bfloat16* wtv = (__hip_bfloat16*)(ws + 4 * ACT + 2 * WT);
  __hip_bfloat16* wtp = (__hip_bfloat16*)(ws + 4 * ACT + 3 * WT);
  __hip_bfloat16* attnbf = xbf;  // alias: x is dead after the QKV GEMM

  // 1) x -> bf16
  {
    int n4 = (M_TOT * DMODEL) / 4;  // 5,242,880
    cvt_bf16_kernel<<<n4 / 256, 256, 0, stream>>>(x, xbf, n4);
  }
  // 2) transpose+convert the 4 weight matrices
  {
    dim3 g(DMODEL / 32, DMODEL / 32, 4), b(32, 8);
    transpose_cvt_kernel<<<g, b, 0, stream>>>(Wq, Wk, Wv, Wp, wtq, wtk, wtv, wtp);
  }
  // 3) fused QKV GEMM: grid (M/256, 3*5)
  {
    dim3 g(M_TOT / 256, 3 * NTC);
    gemm_bt_kernel<true><<<g, 512, 0, stream>>>(
        xbf, wtq, wtk, wtv, bq, bk, bv, (void*)qbf, (void*)kbf, (void*)vbf);
  }
  // 4) per-position attention (+ per_dim_scale), bf16 out over xbf
  attn_kernel<<<M_TOT, 256, 0, stream>>>(qbf, kbf, vbf, pds, attnbf);
  // 5) output projection -> fp32 d_out (128x128 tiles, 2 blocks/CU)
  {
    dim3 g(M_TOT / 128, DMODEL / 128);
    gemm_bt128_kernel<<<g, 256, 0, stream>>>(attnbf, wtp, bp, out);
  }
}